// Round 8
// baseline (332.004 us; speedup 1.0000x reference)
//
#include <hip/hip_runtime.h>
#include <hip/hip_bf16.h>
#include <stdint.h>

#define BATCH 8192
#define NSTATE 30
#define DIN 13
#define E1 256
#define E2 128

typedef short bf16x8 __attribute__((ext_vector_type(8)));
typedef float f32x4 __attribute__((ext_vector_type(4)));

// f32 -> bf16 bits, round-to-nearest-even
__device__ __forceinline__ unsigned short f2b(float f) {
    unsigned u = __float_as_uint(f);
    u += 0x7FFFu + ((u >> 16) & 1u);
    return (unsigned short)(u >> 16);
}
__device__ __forceinline__ float b2f(unsigned short b) {
    return __uint_as_float((unsigned)b << 16);
}
__device__ __forceinline__ unsigned pack2(float a, float b) {     // relu+pack
    return ((unsigned)f2b(fmaxf(b, 0.f)) << 16) | f2b(fmaxf(a, 0.f));
}
__device__ __forceinline__ unsigned pack2n(float a, float b) {    // pack only
    return ((unsigned)f2b(b) << 16) | f2b(a);
}

// combined conv1 weight values (derived R1, verified)
__device__ __forceinline__ float wcat_val(int k, int m, const float* relW, const float* rootW) {
    int part = k >> 7, c = k & 127, grp = m >> 5, mm = m & 31;
    int off = c * 32 + mm;
    if (part == 0) return (grp == 0) ? rootW[4096 + off] + rootW[8192 + off]
                        : (grp == 1) ? relW[off] : relW[3*4096 + off];
    if (part == 1) return (grp == 0) ? relW[1*4096 + off]
                        : (grp == 1) ? relW[6*4096 + off] : relW[5*4096 + off];
    return (grp == 0) ? relW[2*4096 + off]
         : (grp == 1) ? relW[4*4096 + off] : relW[7*4096 + off];
}
__device__ __forceinline__ float wc2_val(int k, int n, const float* relW, const float* rootW) {
    int grp = k >> 5, kk = k & 31;
    int off = kk * 128 + n;
    if (grp == 0) return rootW[4096 + off] + rootW[8192 + off];
    if (grp == 1) return relW[4096 + off];
    return relW[8192 + off];
}

// ---------------------------------------------------------------------------
// k_prep: bias vectors + ALL bf16 MFMA fragment tables (verified decode):
//   entry i -> j=i&7, l=(i>>3)&63, k = ks*32+(l>>4)*8+j, n = nt*16+(l&15)
// ---------------------------------------------------------------------------
__global__ void k_prep(const float* __restrict__ c1_relW, const float* __restrict__ c1_relb,
                       const float* __restrict__ c1_rootW,
                       const float* __restrict__ c2_relW, const float* __restrict__ c2_relb,
                       const float* __restrict__ c2_rootW,
                       const float* __restrict__ wh_W0, const float* __restrict__ wh_W1,
                       const float* __restrict__ wo_W0, const float* __restrict__ wo_W1,
                       const float* __restrict__ wr_W0, const float* __restrict__ wr_W1,
                       const float* __restrict__ v_W0, const float* __restrict__ v_W1,
                       float* __restrict__ bcat, float* __restrict__ bc2,
                       unsigned short* __restrict__ W0b_h, unsigned short* __restrict__ W0b_o,
                       unsigned short* __restrict__ W0b_r,
                       unsigned short* __restrict__ W1f_h, unsigned short* __restrict__ W1f_o,
                       unsigned short* __restrict__ W1f_r,
                       unsigned short* __restrict__ Mf_h, unsigned short* __restrict__ Mf_o,
                       unsigned short* __restrict__ Wcatf, unsigned short* __restrict__ Wc2f,
                       unsigned short* __restrict__ vW0f, unsigned short* __restrict__ vW1f)
{
    int gid = blockIdx.x * blockDim.x + threadIdx.x;
    int gsz = gridDim.x * blockDim.x;

    for (int i = gid; i < 96; i += gsz) {
        int grp = i >> 5, mm = i & 31;
        float v;
        if (grp == 0)      v = c1_relb[32 + mm] + c1_relb[64 + mm];
        else if (grp == 1) v = c1_relb[mm] + c1_relb[128 + mm] + c1_relb[192 + mm];
        else               v = c1_relb[96 + mm] + c1_relb[160 + mm] + c1_relb[224 + mm];
        bcat[i] = v;
    }
    for (int i = gid; i < 128; i += gsz) bc2[i] = c2_relb[128 + i] + c2_relb[256 + i];

    for (int i = gid; i < 2048; i += gsz) {
        int n = i >> 3, j = i & 7;
        W0b_h[i] = (j < 7) ? f2b(wh_W0[j * 256 + n]) : 0;
        W0b_o[i] = (j < 7) ? f2b(wo_W0[j * 256 + n]) : 0;
        W0b_r[i] = (j < 6) ? f2b(wr_W0[j * 256 + n]) : 0;
    }
    for (int i = gid; i < 32768; i += gsz) {
        int j = i & 7, l = (i >> 3) & 63, nt = (i >> 9) & 7, ks = i >> 12;
        int k = ks * 32 + (l >> 4) * 8 + j;
        int n = nt * 16 + (l & 15);
        W1f_h[i] = f2b(wh_W1[k * 128 + n]);
        W1f_o[i] = f2b(wo_W1[k * 128 + n]);
        W1f_r[i] = f2b(wr_W1[k * 128 + n]);
    }
    for (int i = gid; i < 4096; i += gsz) {
        int j = i & 7, l = (i >> 3) & 63, nt = (i >> 9) & 1, ks = i >> 10;
        int k = ks * 32 + (l >> 4) * 8 + j;
        int n = nt * 16 + (l & 15);
        int i0 = k * 32 + n;
        Mf_h[i] = f2b(c1_rootW[i0] + c1_rootW[4*4096 + i0] + c1_rootW[6*4096 + i0] - c1_relW[6*4096 + i0]);
        Mf_o[i] = f2b(c1_rootW[3*4096 + i0] + c1_rootW[5*4096 + i0] + c1_rootW[7*4096 + i0] - c1_relW[7*4096 + i0]);
    }
    for (int i = gid; i < 36864; i += gsz) {
        int j = i & 7, l = (i >> 3) & 63, rem = i >> 9;
        int nt = rem % 6, ks = rem / 6;
        int k = ks * 32 + (l >> 4) * 8 + j;
        int n = nt * 16 + (l & 15);
        Wcatf[i] = f2b(wcat_val(k, n, c1_relW, c1_rootW));
    }
    for (int i = gid; i < 12288; i += gsz) {
        int j = i & 7, l = (i >> 3) & 63, rem = i >> 9;
        int nt = rem & 7, ks = rem >> 3;
        int k = ks * 32 + (l >> 4) * 8 + j;
        int n = nt * 16 + (l & 15);
        Wc2f[i] = f2b(wc2_val(k, n, c2_relW, c2_rootW));
    }
    for (int i = gid; i < 32768; i += gsz) {
        int j = i & 7, l = (i >> 3) & 63, rem = i >> 9;
        int nt = rem & 15, ks = rem >> 4;
        int k = ks * 32 + (l >> 4) * 8 + j;
        int n = nt * 16 + (l & 15);
        vW0f[i] = f2b(v_W0[k * 256 + n]);
    }
    for (int i = gid; i < 32768; i += gsz) {
        int j = i & 7, l = (i >> 3) & 63, rem = i >> 9;
        int nt = rem & 7, ks = rem >> 3;
        int k = ks * 32 + (l >> 4) * 8 + j;
        int n = nt * 16 + (l & 15);
        vW1f[i] = f2b(v_W1[k * 128 + n]);
    }
}

// ---------------------------------------------------------------------------
// mlp_blockC: BARRIER-FREE per-wave pipeline. 512 thr = 8 waves; each wave
// owns 16 rows/tile, 8 tiles/block. hs is wave-private [16][264]; esA aliases
// the wave's OWN region (intra-wave WAR guarded by s_waitcnt lgkmcnt(0)).
// Single __syncthreads after one-time weight staging; none in the tile loop.
// LDS: W0s@0 4KB | Mfs@4K 8KB | W1s@12K 64KB | hs@77824 8x8448B = 142KB tot.
// ---------------------------------------------------------------------------
#define SM_W0   0
#define SM_MF   4096
#define SM_W1   12288
#define SM_HS   77824
#define SM_SZ   (77824 + 8 * 16 * 264 * 2)

template<int NPB, int NODE0, int INOFF, int INDIM, bool TAIL>
__device__ __forceinline__ void mlp_blockC(
    int tile0, const float* __restrict__ state,
    const unsigned short* __restrict__ W0b_g, const float* __restrict__ b0,
    const unsigned short* __restrict__ W1f_g, const float* __restrict__ b1,
    const unsigned short* __restrict__ Mf_g,
    unsigned short* __restrict__ tT, float* __restrict__ sumT,
    unsigned short* __restrict__ eR, int NR, char* smem)
{
    unsigned short* W0s = (unsigned short*)(smem + SM_W0);
    unsigned short* Mfs = (unsigned short*)(smem + SM_MF);
    unsigned short* W1s = (unsigned short*)(smem + SM_W1);

    const int t = threadIdx.x;
    const int lane = t & 63;
    const int w = t >> 6;
    const int l15 = lane & 15;
    const int quad = lane >> 4;
    unsigned short* hw = (unsigned short*)(smem + SM_HS) + w * (16 * 264); // [16][264]
    unsigned short* ew = hw;                                              // alias [16][136]

    // ---- one-time staging ----
    if (t < 256) ((uint4*)W0s)[t] = ((const uint4*)W0b_g)[t];
    #pragma unroll
    for (int i = 0; i < 8; ++i)
        ((uint4*)W1s)[t + 512 * i] = ((const uint4*)W1f_g)[t + 512 * i];
    if constexpr (TAIL)
        ((uint4*)Mfs)[t] = ((const uint4*)Mf_g)[t];

    // biases -> registers (loop-invariant across all 8 tiles)
    f32x4 b0r[16], b1r[8];
    #pragma unroll
    for (int nt = 0; nt < 16; ++nt) {
        float4 bb = *(const float4*)(b0 + nt * 16 + quad * 4);
        b0r[nt] = (f32x4){bb.x, bb.y, bb.z, bb.w};
    }
    #pragma unroll
    for (int nt = 0; nt < 8; ++nt) {
        float4 bb = *(const float4*)(b1 + nt * 16 + quad * 4);
        b1r[nt] = (f32x4){bb.x, bb.y, bb.z, bb.w};
    }
    __syncthreads();   // the ONLY block-wide barrier

    for (int tl = 0; tl < 8; ++tl) {
        const int row0 = (tile0 + tl) * 128;
        const int wrow0 = row0 + w * 16;          // this wave's first row

        // ---- X: contiguous per-lane loads (quad0 lanes only) ----
        bf16x8 bx = {};
        if (quad == 0) {
            int grow = wrow0 + l15;
            int b = grow / NPB;
            int n = grow - b * NPB + NODE0;
            const float* xp = state + ((size_t)b * NSTATE + n) * DIN + INOFF;
            #pragma unroll
            for (int j = 0; j < INDIM; ++j)
                bx[j] = (short)f2b(xp[j]);
        }

        // ---- layer 1 (swapped): lane holds h[r=l15][n=nt*16+quad*4+reg] ----
        #pragma unroll
        for (int nt = 0; nt < 16; ++nt) {
            bf16x8 aw = {};
            if (quad == 0)
                aw = *(const bf16x8*)(W0s + (nt * 16 + l15) * 8);
            f32x4 c = b0r[nt];
            c = __builtin_amdgcn_mfma_f32_16x16x32_bf16(aw, bx, c, 0, 0, 0);
            uint2 pv = {pack2(c[0], c[1]), pack2(c[2], c[3])};
            *(uint2*)(hw + l15 * 264 + nt * 16 + quad * 4) = pv;
        }

        // ---- layer 2 (swapped): lane holds e[r=l15][n=nt*16+quad*4+reg] ----
        f32x4 acc[8];
        #pragma unroll
        for (int nt = 0; nt < 8; ++nt) acc[nt] = b1r[nt];
        #pragma unroll
        for (int ks = 0; ks < 8; ++ks) {
            bf16x8 bh = *(const bf16x8*)(hw + l15 * 264 + ks * 32 + quad * 8);
            #pragma unroll
            for (int nt = 0; nt < 8; ++nt) {
                bf16x8 aw = *(const bf16x8*)(W1s + ((ks * 8 + nt) * 64 + lane) * 8);
                acc[nt] = __builtin_amdgcn_mfma_f32_16x16x32_bf16(aw, bh, acc[nt], 0, 0, 0);
            }
        }

        if constexpr (TAIL) {
            // intra-wave WAR: all hs reads must complete before ew overwrites
            __asm__ __volatile__("s_waitcnt lgkmcnt(0)" ::: "memory");
            #pragma unroll
            for (int nt = 0; nt < 8; ++nt) {
                uint2 pv = {pack2(acc[nt][0], acc[nt][1]), pack2(acc[nt][2], acc[nt][3])};
                *(uint2*)(ew + l15 * 136 + nt * 16 + quad * 4) = pv;
            }

            // t = e @ M (unswapped, verified): D row=quad*4+reg -> e-row, col=l15 -> t-col
            f32x4 tacc[2] = {{0.f,0.f,0.f,0.f},{0.f,0.f,0.f,0.f}};
            #pragma unroll
            for (int ks = 0; ks < 4; ++ks) {
                bf16x8 ae = *(const bf16x8*)(ew + l15 * 136 + ks * 32 + quad * 8);
                #pragma unroll
                for (int nt = 0; nt < 2; ++nt) {
                    bf16x8 bm = *(const bf16x8*)(Mfs + ((ks * 2 + nt) * 64 + lane) * 8);
                    tacc[nt] = __builtin_amdgcn_mfma_f32_16x16x32_bf16(ae, bm, tacc[nt], 0, 0, 0);
                }
            }
            #pragma unroll
            for (int nt = 0; nt < 2; ++nt) {
                uint2 pv = {pack2n(tacc[nt][0], tacc[nt][1]), pack2n(tacc[nt][2], tacc[nt][3])};
                *(uint2*)(tT + (size_t)(nt * 16 + l15) * NR + wrow0 + quad * 4) = pv;
            }

            // per-wave col-sums: lane sums 2 columns over its wave's 16 rows
            #pragma unroll
            for (int cc = 0; cc < 2; ++cc) {
                int c = lane + cc * 64;
                float s = 0.f;
                int bcur = wrow0 / NPB;
                #pragma unroll
                for (int r = 0; r < 16; ++r) {
                    int b = (wrow0 + r) / NPB;
                    if (b != bcur) {
                        atomicAdd(&sumT[(size_t)c * BATCH + bcur], s);
                        s = 0.f; bcur = b;
                    }
                    s += b2f(ew[r * 136 + c]);
                }
                atomicAdd(&sumT[(size_t)c * BATCH + bcur], s);
            }
        } else {
            // root: direct row-major global store eR[row][n]
            #pragma unroll
            for (int nt = 0; nt < 8; ++nt) {
                uint2 pv = {pack2(acc[nt][0], acc[nt][1]), pack2(acc[nt][2], acc[nt][3])};
                *(uint2*)(eR + (size_t)(wrow0 + l15) * 128 + nt * 16 + quad * 4) = pv;
            }
        }
        __asm__ __volatile__("" ::: "memory");   // keep iteration LDS order
    }
}

__global__ __launch_bounds__(512, 2) void k_mlpC(
    const float* __restrict__ state,
    const unsigned short* __restrict__ W0b_h, const float* __restrict__ b0_h,
    const unsigned short* __restrict__ W1f_h, const float* __restrict__ b1_h,
    const unsigned short* __restrict__ Mf_h, unsigned short* __restrict__ tT_h,
    float* __restrict__ shT,
    const unsigned short* __restrict__ W0b_o, const float* __restrict__ b0_o,
    const unsigned short* __restrict__ W1f_o, const float* __restrict__ b1_o,
    const unsigned short* __restrict__ Mf_o, unsigned short* __restrict__ tT_o,
    float* __restrict__ soT,
    const unsigned short* __restrict__ W0b_r, const float* __restrict__ b0_r,
    const unsigned short* __restrict__ W1f_r, const float* __restrict__ b1_r,
    unsigned short* __restrict__ eR)
{
    __shared__ __align__(16) char smem[SM_SZ];
    int bid = blockIdx.x;
    if (bid < 160)
        mlp_blockC<20, 0, 6, 7, true>(bid * 8, state, W0b_h, b0_h, W1f_h, b1_h,
                                      Mf_h, tT_h, shT, nullptr, 163840, smem);
    else if (bid < 240)
        mlp_blockC<10, 20, 6, 7, true>((bid - 160) * 8, state, W0b_o, b0_o, W1f_o, b1_o,
                                       Mf_o, tT_o, soT, nullptr, 81920, smem);
    else
        mlp_blockC<1, 0, 0, 6, false>((bid - 240) * 8, state, W0b_r, b0_r, W1f_r, b1_r,
                                      nullptr, nullptr, nullptr, eR, 8192, smem);
}

// ---------------------------------------------------------------------------
// k_u2: [xr|ch|co](96) = U(384) @ Wcat + bcat via MFMA; 32 b/block.
// ---------------------------------------------------------------------------
__global__ __launch_bounds__(256) void k_u2(
    const unsigned short* __restrict__ eR,
    const float* __restrict__ shT, const float* __restrict__ soT,
    const unsigned short* __restrict__ Wcatf, const float* __restrict__ bcat,
    unsigned short* __restrict__ xrT, float* __restrict__ chT, float* __restrict__ coT)
{
    __shared__ __align__(16) unsigned short Ub[32 * 400];
    const int t = threadIdx.x, lane = t & 63, w = t >> 6;
    const int l15 = lane & 15, quad = lane >> 4;
    const int b0 = blockIdx.x * 32;

    {
        int b = t >> 3, q = t & 7;
        const uint4* src = (const uint4*)(eR + (size_t)(b0 + b) * 128 + q * 16);
        uint4 v0 = src[0], v1 = src[1];
        uint4* dst = (uint4*)(Ub + b * 400 + q * 16);
        dst[0] = v0; dst[1] = v1;
    }
    for (int idx = t; idx < 8192; idx += 256) {
        int kk = idx >> 5, b = idx & 31;
        float v = (kk < 128) ? shT[(size_t)kk * BATCH + b0 + b]
                             : soT[(size_t)(kk - 128) * BATCH + b0 + b];
        Ub[b * 400 + 128 + kk] = f2b(v);
    }
    __syncthreads();

    const int mt = w >> 1, ntg = (w & 1) * 3;
    f32x4 acc[3];
    #pragma unroll
    for (int q = 0; q < 3; ++q) {
        float bias = bcat[(ntg + q) * 16 + l15];
        acc[q] = (f32x4){bias, bias, bias, bias};
    }
    #pragma unroll
    for (int ks = 0; ks < 12; ++ks) {
        bf16x8 a = *(const bf16x8*)(Ub + (mt * 16 + l15) * 400 + ks * 32 + quad * 8);
        #pragma unroll
        for (int q = 0; q < 3; ++q) {
            bf16x8 bw = *(const bf16x8*)(Wcatf + ((ks * 6 + ntg + q) * 64 + lane) * 8);
            acc[q] = __builtin_amdgcn_mfma_f32_16x16x32_bf16(a, bw, acc[q], 0, 0, 0);
        }
    }
    int brow = b0 + mt * 16 + quad * 4;
    #pragma unroll
    for (int q = 0; q < 3; ++q) {
        int n = (ntg + q) * 16 + l15;
        #pragma unroll
        for (int reg = 0; reg < 4; ++reg) {
            float v = acc[q][reg];
            int b = brow + reg;
            if (n < 32)      xrT[(size_t)n * BATCH + b] = f2b(fmaxf(v, 0.f));
            else if (n < 64) chT[(size_t)(n - 32) * BATCH + b] = v;
            else             coT[(size_t)(n - 64) * BATCH + b] = v;
        }
    }
}

// ---------------------------------------------------------------------------
// k_sM: s2[b][m] = sum_n relu(c[b][m] + t[b,n][m]); h and o merged.
// ---------------------------------------------------------------------------
__global__ __launch_bounds__(256) void k_sM(
    const unsigned short* __restrict__ tT_h, const unsigned short* __restrict__ tT_o,
    const float* __restrict__ chT, const float* __restrict__ coT,
    unsigned short* __restrict__ s2hT, unsigned short* __restrict__ s2oT)
{
    int bid = blockIdx.x;
    if (bid < 1024) {
        int gid = bid * 256 + threadIdx.x;
        int b = gid & (BATCH - 1), m = gid >> 13;
        const unsigned short* p = tT_h + (size_t)m * 163840 + b * 20;
        float c = chT[(size_t)m * BATCH + b];
        float s = 0.f;
        #pragma unroll
        for (int n = 0; n < 20; ++n) s += fmaxf(c + b2f(p[n]), 0.f);
        s2hT[(size_t)m * BATCH + b] = f2b(s);
    } else {
        int gid = (bid - 1024) * 256 + threadIdx.x;
        int b = gid & (BATCH - 1), m = gid >> 13;
        const unsigned short* p = tT_o + (size_t)m * 81920 + b * 10;
        float c = coT[(size_t)m * BATCH + b];
        float s = 0.f;
        #pragma unroll
        for (int n = 0; n < 10; ++n) s += fmaxf(c + b2f(p[n]), 0.f);
        s2oT[(size_t)m * BATCH + b] = f2b(s);
    }
}

// ---------------------------------------------------------------------------
// k_v: fused c2 + value-MLP via MFMA (verified). 32 b/block, 256 blocks.
// ---------------------------------------------------------------------------
__global__ __launch_bounds__(256) void k_v(
    const unsigned short* __restrict__ xrT, const unsigned short* __restrict__ s2hT,
    const unsigned short* __restrict__ s2oT,
    const unsigned short* __restrict__ Wc2f, const float* __restrict__ bc2,
    const unsigned short* __restrict__ vW0f, const float* __restrict__ vb0,
    const unsigned short* __restrict__ vW1f, const float* __restrict__ vb1,
    const float* __restrict__ vW2, const float* __restrict__ vb2,
    float* __restrict__ out)
{
    __shared__ __align__(16) unsigned short Vb[32 * 104];
    __shared__ __align__(16) unsigned short Hb[32 * 136];
    __shared__ __align__(16) unsigned short V1b[32 * 264];
    __shared__ __align__(16) float V2b[32 * 132];
    const int t = threadIdx.x, lane = t & 63, w = t >> 6;
    const int l15 = lane & 15, quad = lane >> 4;
    const int b0 = blockIdx.x * 32;
    const int mt = w >> 1, nh = w & 1;
    const int rowb = mt * 16 + quad * 4;

    for (int idx = t; idx < 32 * 96; idx += 256) {
        int k = idx >> 5, b = idx & 31;
        unsigned short v;
        if (k < 32)      v = xrT[(size_t)k * BATCH + b0 + b];
        else if (k < 64) v = s2hT[(size_t)(k - 32) * BATCH + b0 + b];
        else             v = s2oT[(size_t)(k - 64) * BATCH + b0 + b];
        Vb[b * 104 + k] = v;
    }
    __syncthreads();

    { // c2
        const int ntg = nh * 4;
        f32x4 acc[4];
        #pragma unroll
        for (int q = 0; q < 4; ++q) {
            float bias = bc2[(ntg + q) * 16 + l15];
            acc[q] = (f32x4){bias, bias, bias, bias};
        }
        #pragma unroll
        for (int ks = 0; ks < 3; ++ks) {
            bf16x8 a = *(const bf16x8*)(Vb + (mt * 16 + l15) * 104 + ks * 32 + quad * 8);
            #pragma unroll
            for (int q = 0; q < 4; ++q) {
                bf16x8 bw = *(const bf16x8*)(Wc2f + ((ks * 8 + ntg + q) * 64 + lane) * 8);
                acc[q] = __builtin_amdgcn_mfma_f32_16x16x32_bf16(a, bw, acc[q], 0, 0, 0);
            }
        }
        #pragma unroll
        for (int q = 0; q < 4; ++q)
            #pragma unroll
            for (int reg = 0; reg < 4; ++reg)
                Hb[(rowb + reg) * 136 + (ntg + q) * 16 + l15] = f2b(fmaxf(acc[q][reg], 0.f));
    }
    __syncthreads();

    { // v1
        const int ntg = nh * 8;
        f32x4 acc[8];
        #pragma unroll
        for (int q = 0; q < 8; ++q) {
            float bias = vb0[(ntg + q) * 16 + l15];
            acc[q] = (f32x4){bias, bias, bias, bias};
        }
        #pragma unroll
        for (int ks = 0; ks < 4; ++ks) {
            bf16x8 a = *(const bf16x8*)(Hb + (mt * 16 + l15) * 136 + ks * 32 + quad * 8);
            #pragma unroll
            for (int q = 0; q < 8; ++q) {
                bf16x8 bw = *(const bf16x8*)(vW0f + ((ks * 16 + ntg + q) * 64 + lane) * 8);
                acc[q] = __builtin_amdgcn_mfma_f32_16x16x32_bf16(a, bw, acc[q], 0, 0, 0);
            }
        }
        __syncthreads();
        #pragma unroll
        for (int q = 0; q < 8; ++q)
            #pragma unroll
            for (int reg = 0; reg < 4; ++reg)
                V1b[(rowb + reg) * 264 + (ntg + q) * 16 + l15] = f2b(fmaxf(acc[q][reg], 0.f));
    }
    __syncthreads();

    { // v2
        const int ntg = nh * 4;
        f32x4 acc[4];
        #pragma unroll
        for (int q = 0; q < 4; ++q) {
            float bias = vb1[(ntg + q) * 16 + l15];
            acc[q] = (f32x4){bias, bias, bias, bias};
        }
        #pragma unroll
        for (int ks = 0; ks < 8; ++ks) {
            bf16x8 a = *(const bf16x8*)(V1b + (mt * 16 + l15) * 264 + ks * 32 + quad * 8);
            #pragma unroll
            for (int q = 0; q < 4; ++q) {
                bf16x8 bw = *(const bf16x8*)(vW1f + ((ks * 8 + ntg + q) * 64 + lane) * 8);
                acc[q] = __builtin_amdgcn_mfma_f32_16x16x32_bf16(a, bw, acc[q], 0, 0, 0);
            }
        }
        #pragma unroll
        for (int q = 0; q < 4; ++q)
            #pragma unroll
            for (int reg = 0; reg < 4; ++reg)
                V2b[(rowb + reg) * 132 + (ntg + q) * 16 + l15] = fmaxf(acc[q][reg], 0.f);
    }
    __syncthreads();

    if (t < 32) {
        float acc = vb2[0];
        for (int k = 0; k < 128; ++k)
            acc = fmaf(V2b[t * 132 + k], vW2[k], acc);
        out[b0 + t] = acc;
    }
}

// ---------------------------------------------------------------------------
extern "C" void kernel_launch(void* const* d_in, const int* in_sizes, int n_in,
                              void* d_out, int out_size, void* d_ws, size_t ws_size,
                              hipStream_t stream)
{
    const float* state   = (const float*)d_in[0];
    const float* wr_W0   = (const float*)d_in[2];
    const float* wr_b0   = (const float*)d_in[3];
    const float* wr_W1   = (const float*)d_in[4];
    const float* wr_b1   = (const float*)d_in[5];
    const float* wh_W0   = (const float*)d_in[6];
    const float* wh_b0   = (const float*)d_in[7];
    const float* wh_W1   = (const float*)d_in[8];
    const float* wh_b1   = (const float*)d_in[9];
    const float* wo_W0   = (const float*)d_in[10];
    const float* wo_b0   = (const float*)d_in[11];
    const float* wo_W1   = (const float*)d_in[12];
    const float* wo_b1   = (const float*)d_in[13];
    const float* c1_relW = (const float*)d_in[14];
    const float* c1_relb = (const float*)d_in[15];
    const float* c1_rootW= (const float*)d_in[16];
    const float* c2_relW = (const float*)d_in[17];
    const float* c2_relb = (const float*)d_in[18];
    const float* c2_rootW= (const float*)d_in[19];
    const float* v_W0    = (const float*)d_in[20];
    const float* v_b0    = (const float*)d_in[21];
    const float* v_W1    = (const float*)d_in[22];
    const float* v_b1    = (const float*)d_in[23];
    const float* v_W2    = (const float*)d_in[24];
    const float* v_b2    = (const float*)d_in[25];

    char* ws = (char*)d_ws;
    size_t off = 0;
    auto alloc = [&](size_t bytes) -> char* {
        char* p = ws + off;
        off = (off + bytes + 255) & ~(size_t)255;
        return p;
    };
    float* shT  = (float*)alloc((size_t)128 * BATCH * 4);
    float* soT  = (float*)alloc((size_t)128 * BATCH * 4);
    unsigned short* tT_h = (unsigned short*)alloc((size_t)32 * 163840 * 2);
    unsigned short* tT_o = (unsigned short*)alloc((size_t)32 * 81920 * 2);
    unsigned short* eR   = (unsigned short*)alloc((size_t)BATCH * 128 * 2);
    unsigned short* xrT  = (unsigned short*)alloc((size_t)32 * BATCH * 2);
    float* chT  = (float*)alloc((size_t)32 * BATCH * 4);
    float* coT  = (float*)alloc((size_t)32 * BATCH * 4);
    unsigned short* s2hT = (unsigned short*)alloc((size_t)32 * BATCH * 2);
    unsigned short* s2oT = (unsigned short*)alloc((size_t)32 * BATCH * 2);
    float* bcat = (float*)alloc(96 * 4);
    float* bc2  = (float*)alloc(128 * 4);
    unsigned short* W0b_h = (unsigned short*)alloc(2048 * 2);
    unsigned short* W0b_o = (unsigned short*)alloc(2048 * 2);
    unsigned short* W0b_r = (unsigned short*)alloc(2048 * 2);
    unsigned short* W1f_h = (unsigned short*)alloc(32768 * 2);
    unsigned short* W1f_o = (unsigned short*)alloc(32768 * 2);
    unsigned short* W1f_r = (unsigned short*)alloc(32768 * 2);
    unsigned short* Mf_h  = (unsigned short*)alloc(4096 * 2);
    unsigned short* Mf_o  = (unsigned short*)alloc(4096 * 2);
    unsigned short* Wcatf = (unsigned short*)alloc(36864 * 2);
    unsigned short* Wc2f  = (unsigned short*)alloc(12288 * 2);
    unsigned short* vW0f  = (unsigned short*)alloc(32768 * 2);
    unsigned short* vW1f  = (unsigned short*)alloc(32768 * 2);
    (void)ws_size; (void)in_sizes; (void)n_in; (void)out_size;

    hipMemsetAsync(shT, 0, (size_t)2 * 128 * BATCH * 4, stream);

    k_prep<<<256, 256, 0, stream>>>(c1_relW, c1_relb, c1_rootW, c2_relW, c2_relb, c2_rootW,
                                    wh_W0, wh_W1, wo_W0, wo_W1, wr_W0, wr_W1, v_W0, v_W1,
                                    bcat, bc2, W0b_h, W0b_o, W0b_r, W1f_h, W1f_o, W1f_r,
                                    Mf_h, Mf_o, Wcatf, Wc2f, vW0f, vW1f);

    k_mlpC<<<248, 512, 0, stream>>>(state,
                                    W0b_h, wh_b0, W1f_h, wh_b1, Mf_h, tT_h, shT,
                                    W0b_o, wo_b0, W1f_o, wo_b1, Mf_o, tT_o, soT,
                                    W0b_r, wr_b0, W1f_r, wr_b1, eR);
    k_u2<<<256, 256, 0, stream>>>(eR, shT, soT, Wcatf, bcat, xrT, chT, coT);
    k_sM<<<2048, 256, 0, stream>>>(tT_h, tT_o, chT, coT, s2hT, s2oT);
    k_v<<<256, 256, 0, stream>>>(xrT, s2hT, s2oT, Wc2f, bc2, vW0f, v_b0, vW1f, v_b1,
                                 v_W2, v_b2, (float*)d_out);
}

// Round 9
// 192.787 us; speedup vs baseline: 1.7221x; 1.7221x over previous
//
#include <hip/hip_runtime.h>
#include <hip/hip_bf16.h>
#include <stdint.h>

#define BATCH 8192
#define NSTATE 30
#define DIN 13
#define E1 256
#define E2 128

typedef short bf16x8 __attribute__((ext_vector_type(8)));
typedef float f32x4 __attribute__((ext_vector_type(4)));

// f32 -> bf16 bits, round-to-nearest-even
__device__ __forceinline__ unsigned short f2b(float f) {
    unsigned u = __float_as_uint(f);
    u += 0x7FFFu + ((u >> 16) & 1u);
    return (unsigned short)(u >> 16);
}
__device__ __forceinline__ float b2f(unsigned short b) {
    return __uint_as_float((unsigned)b << 16);
}
__device__ __forceinline__ unsigned pack2(float a, float b) {     // relu+pack
    return ((unsigned)f2b(fmaxf(b, 0.f)) << 16) | f2b(fmaxf(a, 0.f));
}
__device__ __forceinline__ unsigned pack2n(float a, float b) {    // pack only
    return ((unsigned)f2b(b) << 16) | f2b(a);
}

// combined conv1 weight values (derived R1, verified)
__device__ __forceinline__ float wcat_val(int k, int m, const float* relW, const float* rootW) {
    int part = k >> 7, c = k & 127, grp = m >> 5, mm = m & 31;
    int off = c * 32 + mm;
    if (part == 0) return (grp == 0) ? rootW[4096 + off] + rootW[8192 + off]
                        : (grp == 1) ? relW[off] : relW[3*4096 + off];
    if (part == 1) return (grp == 0) ? relW[1*4096 + off]
                        : (grp == 1) ? relW[6*4096 + off] : relW[5*4096 + off];
    return (grp == 0) ? relW[2*4096 + off]
         : (grp == 1) ? relW[4*4096 + off] : relW[7*4096 + off];
}
__device__ __forceinline__ float wc2_val(int k, int n, const float* relW, const float* rootW) {
    int grp = k >> 5, kk = k & 31;
    int off = kk * 128 + n;
    if (grp == 0) return rootW[4096 + off] + rootW[8192 + off];
    if (grp == 1) return relW[4096 + off];
    return relW[8192 + off];
}

// ---------------------------------------------------------------------------
// k_prep: bias vectors + ALL bf16 MFMA fragment tables (verified decode):
//   entry i -> j=i&7, l=(i>>3)&63, k = ks*32+(l>>4)*8+j, n = nt*16+(l&15)
// ---------------------------------------------------------------------------
__global__ void k_prep(const float* __restrict__ c1_relW, const float* __restrict__ c1_relb,
                       const float* __restrict__ c1_rootW,
                       const float* __restrict__ c2_relW, const float* __restrict__ c2_relb,
                       const float* __restrict__ c2_rootW,
                       const float* __restrict__ wh_W0, const float* __restrict__ wh_W1,
                       const float* __restrict__ wo_W0, const float* __restrict__ wo_W1,
                       const float* __restrict__ wr_W0, const float* __restrict__ wr_W1,
                       const float* __restrict__ v_W0, const float* __restrict__ v_W1,
                       float* __restrict__ bcat, float* __restrict__ bc2,
                       unsigned short* __restrict__ W0b_h, unsigned short* __restrict__ W0b_o,
                       unsigned short* __restrict__ W0b_r,
                       unsigned short* __restrict__ W1f_h, unsigned short* __restrict__ W1f_o,
                       unsigned short* __restrict__ W1f_r,
                       unsigned short* __restrict__ Mf_h, unsigned short* __restrict__ Mf_o,
                       unsigned short* __restrict__ Wcatf, unsigned short* __restrict__ Wc2f,
                       unsigned short* __restrict__ vW0f, unsigned short* __restrict__ vW1f)
{
    int gid = blockIdx.x * blockDim.x + threadIdx.x;
    int gsz = gridDim.x * blockDim.x;

    for (int i = gid; i < 96; i += gsz) {
        int grp = i >> 5, mm = i & 31;
        float v;
        if (grp == 0)      v = c1_relb[32 + mm] + c1_relb[64 + mm];
        else if (grp == 1) v = c1_relb[mm] + c1_relb[128 + mm] + c1_relb[192 + mm];
        else               v = c1_relb[96 + mm] + c1_relb[160 + mm] + c1_relb[224 + mm];
        bcat[i] = v;
    }
    for (int i = gid; i < 128; i += gsz) bc2[i] = c2_relb[128 + i] + c2_relb[256 + i];

    for (int i = gid; i < 2048; i += gsz) {
        int n = i >> 3, j = i & 7;
        W0b_h[i] = (j < 7) ? f2b(wh_W0[j * 256 + n]) : 0;
        W0b_o[i] = (j < 7) ? f2b(wo_W0[j * 256 + n]) : 0;
        W0b_r[i] = (j < 6) ? f2b(wr_W0[j * 256 + n]) : 0;
    }
    for (int i = gid; i < 32768; i += gsz) {
        int j = i & 7, l = (i >> 3) & 63, nt = (i >> 9) & 7, ks = i >> 12;
        int k = ks * 32 + (l >> 4) * 8 + j;
        int n = nt * 16 + (l & 15);
        W1f_h[i] = f2b(wh_W1[k * 128 + n]);
        W1f_o[i] = f2b(wo_W1[k * 128 + n]);
        W1f_r[i] = f2b(wr_W1[k * 128 + n]);
    }
    for (int i = gid; i < 4096; i += gsz) {
        int j = i & 7, l = (i >> 3) & 63, nt = (i >> 9) & 1, ks = i >> 10;
        int k = ks * 32 + (l >> 4) * 8 + j;
        int n = nt * 16 + (l & 15);
        int i0 = k * 32 + n;
        Mf_h[i] = f2b(c1_rootW[i0] + c1_rootW[4*4096 + i0] + c1_rootW[6*4096 + i0] - c1_relW[6*4096 + i0]);
        Mf_o[i] = f2b(c1_rootW[3*4096 + i0] + c1_rootW[5*4096 + i0] + c1_rootW[7*4096 + i0] - c1_relW[7*4096 + i0]);
    }
    for (int i = gid; i < 36864; i += gsz) {
        int j = i & 7, l = (i >> 3) & 63, rem = i >> 9;
        int nt = rem % 6, ks = rem / 6;
        int k = ks * 32 + (l >> 4) * 8 + j;
        int n = nt * 16 + (l & 15);
        Wcatf[i] = f2b(wcat_val(k, n, c1_relW, c1_rootW));
    }
    for (int i = gid; i < 12288; i += gsz) {
        int j = i & 7, l = (i >> 3) & 63, rem = i >> 9;
        int nt = rem & 7, ks = rem >> 3;
        int k = ks * 32 + (l >> 4) * 8 + j;
        int n = nt * 16 + (l & 15);
        Wc2f[i] = f2b(wc2_val(k, n, c2_relW, c2_rootW));
    }
    for (int i = gid; i < 32768; i += gsz) {
        int j = i & 7, l = (i >> 3) & 63, rem = i >> 9;
        int nt = rem & 15, ks = rem >> 4;
        int k = ks * 32 + (l >> 4) * 8 + j;
        int n = nt * 16 + (l & 15);
        vW0f[i] = f2b(v_W0[k * 256 + n]);
    }
    for (int i = gid; i < 32768; i += gsz) {
        int j = i & 7, l = (i >> 3) & 63, rem = i >> 9;
        int nt = rem & 7, ks = rem >> 3;
        int k = ks * 32 + (l >> 4) * 8 + j;
        int n = nt * 16 + (l & 15);
        vW1f[i] = f2b(v_W1[k * 128 + n]);
    }
}

// ---------------------------------------------------------------------------
// mlp_blockD: barrier-free per-wave pipeline, WAVE-CONTIGUOUS rows.
// Wave w owns 128 contiguous rows (8 sub-tiles of 16); per-b sums accumulate
// in REGISTERS across sub-tiles; interior b's -> plain coalesced stores,
// boundary b's -> coalesced b-major atomics (sum[b*128+c], 64 lanes = 4 lines).
// LDS: W0s@0 4KB | Mfs@4K 8KB | W1s@12K 64KB | hs@77824 8x8448B = 142KB.
// ---------------------------------------------------------------------------
#define SM_W0   0
#define SM_MF   4096
#define SM_W1   12288
#define SM_HS   77824
#define SM_SZ   (77824 + 8 * 16 * 264 * 2)

template<int NPB, int NODE0, int INOFF, int INDIM, bool TAIL>
__device__ __forceinline__ void mlp_blockD(
    int blkrow0, const float* __restrict__ state,
    const unsigned short* __restrict__ W0b_g, const float* __restrict__ b0,
    const unsigned short* __restrict__ W1f_g, const float* __restrict__ b1,
    const unsigned short* __restrict__ Mf_g,
    unsigned short* __restrict__ tT, float* __restrict__ sumB,
    unsigned short* __restrict__ eR, int NR, char* smem)
{
    unsigned short* W0s = (unsigned short*)(smem + SM_W0);
    unsigned short* Mfs = (unsigned short*)(smem + SM_MF);
    unsigned short* W1s = (unsigned short*)(smem + SM_W1);

    const int t = threadIdx.x;
    const int lane = t & 63;
    const int w = t >> 6;
    const int l15 = lane & 15;
    const int quad = lane >> 4;
    const int R0 = blkrow0 + w * 128;     // this wave's 128 contiguous rows
    unsigned short* hw = (unsigned short*)(smem + SM_HS) + w * (16 * 264); // [16][264]
    unsigned short* ew = hw;                                              // alias [16][136]

    // ---- one-time staging ----
    if (t < 256) ((uint4*)W0s)[t] = ((const uint4*)W0b_g)[t];
    #pragma unroll
    for (int i = 0; i < 8; ++i)
        ((uint4*)W1s)[t + 512 * i] = ((const uint4*)W1f_g)[t + 512 * i];
    if constexpr (TAIL)
        ((uint4*)Mfs)[t] = ((const uint4*)Mf_g)[t];

    f32x4 b0r[16], b1r[8];
    #pragma unroll
    for (int nt = 0; nt < 16; ++nt) {
        float4 bb = *(const float4*)(b0 + nt * 16 + quad * 4);
        b0r[nt] = (f32x4){bb.x, bb.y, bb.z, bb.w};
    }
    #pragma unroll
    for (int nt = 0; nt < 8; ++nt) {
        float4 bb = *(const float4*)(b1 + nt * 16 + quad * 4);
        b1r[nt] = (f32x4){bb.x, bb.y, bb.z, bb.w};
    }
    __syncthreads();   // the ONLY block-wide barrier

    // register sum state (cols 2*lane, 2*lane+1), carried across sub-tiles
    float s0 = 0.f, s1 = 0.f;
    int bcur = R0 / NPB;

    for (int sub = 0; sub < 8; ++sub) {
        const int wrow0 = R0 + sub * 16;

        // ---- X: contiguous per-lane loads (quad0 lanes only) ----
        bf16x8 bx = {};
        if (quad == 0) {
            int grow = wrow0 + l15;
            int b = grow / NPB;
            int n = grow - b * NPB + NODE0;
            const float* xp = state + ((size_t)b * NSTATE + n) * DIN + INOFF;
            #pragma unroll
            for (int j = 0; j < INDIM; ++j)
                bx[j] = (short)f2b(xp[j]);
        }

        // ---- layer 1 (swapped): lane holds h[r=l15][n=nt*16+quad*4+reg] ----
        #pragma unroll
        for (int nt = 0; nt < 16; ++nt) {
            bf16x8 aw = {};
            if (quad == 0)
                aw = *(const bf16x8*)(W0s + (nt * 16 + l15) * 8);
            f32x4 c = b0r[nt];
            c = __builtin_amdgcn_mfma_f32_16x16x32_bf16(aw, bx, c, 0, 0, 0);
            uint2 pv = {pack2(c[0], c[1]), pack2(c[2], c[3])};
            *(uint2*)(hw + l15 * 264 + nt * 16 + quad * 4) = pv;
        }

        // ---- layer 2 (swapped): lane holds e[r=l15][n=nt*16+quad*4+reg] ----
        f32x4 acc[8];
        #pragma unroll
        for (int nt = 0; nt < 8; ++nt) acc[nt] = b1r[nt];
        #pragma unroll
        for (int ks = 0; ks < 8; ++ks) {
            bf16x8 bh = *(const bf16x8*)(hw + l15 * 264 + ks * 32 + quad * 8);
            #pragma unroll
            for (int nt = 0; nt < 8; ++nt) {
                bf16x8 aw = *(const bf16x8*)(W1s + ((ks * 8 + nt) * 64 + lane) * 8);
                acc[nt] = __builtin_amdgcn_mfma_f32_16x16x32_bf16(aw, bh, acc[nt], 0, 0, 0);
            }
        }

        if constexpr (TAIL) {
            // intra-wave WAR: hs reads complete before ew overwrite
            __asm__ __volatile__("s_waitcnt lgkmcnt(0)" ::: "memory");
            #pragma unroll
            for (int nt = 0; nt < 8; ++nt) {
                uint2 pv = {pack2(acc[nt][0], acc[nt][1]), pack2(acc[nt][2], acc[nt][3])};
                *(uint2*)(ew + l15 * 136 + nt * 16 + quad * 4) = pv;
            }

            // t = e @ M (unswapped, verified)
            f32x4 tacc[2] = {{0.f,0.f,0.f,0.f},{0.f,0.f,0.f,0.f}};
            #pragma unroll
            for (int ks = 0; ks < 4; ++ks) {
                bf16x8 ae = *(const bf16x8*)(ew + l15 * 136 + ks * 32 + quad * 8);
                #pragma unroll
                for (int nt = 0; nt < 2; ++nt) {
                    bf16x8 bm = *(const bf16x8*)(Mfs + ((ks * 2 + nt) * 64 + lane) * 8);
                    tacc[nt] = __builtin_amdgcn_mfma_f32_16x16x32_bf16(ae, bm, tacc[nt], 0, 0, 0);
                }
            }
            #pragma unroll
            for (int nt = 0; nt < 2; ++nt) {
                uint2 pv = {pack2n(tacc[nt][0], tacc[nt][1]), pack2n(tacc[nt][2], tacc[nt][3])};
                *(uint2*)(tT + (size_t)(nt * 16 + l15) * NR + wrow0 + quad * 4) = pv;
            }

            // per-b sums: lane reads cols (2*lane, 2*lane+1) of each row,
            // accumulates in registers, flushes at b boundaries.
            #pragma unroll
            for (int r = 0; r < 16; ++r) {
                int b = (wrow0 + r) / NPB;
                if (b != bcur) {
                    bool interior = (bcur * NPB >= R0) && ((bcur + 1) * NPB <= R0 + 128);
                    float* dst = sumB + (size_t)bcur * 128 + 2 * lane;
                    if (interior) { dst[0] = s0; dst[1] = s1; }
                    else { atomicAdd(dst, s0); atomicAdd(dst + 1, s1); }
                    s0 = 0.f; s1 = 0.f; bcur = b;
                }
                unsigned v = *(const unsigned*)(ew + r * 136 + lane * 2);
                s0 += b2f((unsigned short)v);
                s1 += b2f((unsigned short)(v >> 16));
            }
            if (sub == 7) {   // final flush (always a boundary b -> atomic-safe test)
                bool interior = (bcur * NPB >= R0) && ((bcur + 1) * NPB <= R0 + 128);
                float* dst = sumB + (size_t)bcur * 128 + 2 * lane;
                if (interior) { dst[0] = s0; dst[1] = s1; }
                else { atomicAdd(dst, s0); atomicAdd(dst + 1, s1); }
            }
        } else {
            // root: direct row-major global store eR[row][n]
            #pragma unroll
            for (int nt = 0; nt < 8; ++nt) {
                uint2 pv = {pack2(acc[nt][0], acc[nt][1]), pack2(acc[nt][2], acc[nt][3])};
                *(uint2*)(eR + (size_t)(wrow0 + l15) * 128 + nt * 16 + quad * 4) = pv;
            }
        }
        __asm__ __volatile__("" ::: "memory");   // keep iteration LDS order
    }
}

__global__ __launch_bounds__(512, 2) void k_mlpD(
    const float* __restrict__ state,
    const unsigned short* __restrict__ W0b_h, const float* __restrict__ b0_h,
    const unsigned short* __restrict__ W1f_h, const float* __restrict__ b1_h,
    const unsigned short* __restrict__ Mf_h, unsigned short* __restrict__ tT_h,
    float* __restrict__ shB,
    const unsigned short* __restrict__ W0b_o, const float* __restrict__ b0_o,
    const unsigned short* __restrict__ W1f_o, const float* __restrict__ b1_o,
    const unsigned short* __restrict__ Mf_o, unsigned short* __restrict__ tT_o,
    float* __restrict__ soB,
    const unsigned short* __restrict__ W0b_r, const float* __restrict__ b0_r,
    const unsigned short* __restrict__ W1f_r, const float* __restrict__ b1_r,
    unsigned short* __restrict__ eR)
{
    __shared__ __align__(16) char smem[SM_SZ];
    int bid = blockIdx.x;
    if (bid < 160)
        mlp_blockD<20, 0, 6, 7, true>(bid * 1024, state, W0b_h, b0_h, W1f_h, b1_h,
                                      Mf_h, tT_h, shB, nullptr, 163840, smem);
    else if (bid < 240)
        mlp_blockD<10, 20, 6, 7, true>((bid - 160) * 1024, state, W0b_o, b0_o, W1f_o, b1_o,
                                       Mf_o, tT_o, soB, nullptr, 81920, smem);
    else
        mlp_blockD<1, 0, 0, 6, false>((bid - 240) * 1024, state, W0b_r, b0_r, W1f_r, b1_r,
                                      nullptr, nullptr, nullptr, eR, 8192, smem);
}

// ---------------------------------------------------------------------------
// k_u2: [xr|ch|co](96) = U(384) @ Wcat + bcat via MFMA; 32 b/block.
// sh/so now b-major [b][128].
// ---------------------------------------------------------------------------
__global__ __launch_bounds__(256) void k_u2(
    const unsigned short* __restrict__ eR,
    const float* __restrict__ shB, const float* __restrict__ soB,
    const unsigned short* __restrict__ Wcatf, const float* __restrict__ bcat,
    unsigned short* __restrict__ xrT, float* __restrict__ chT, float* __restrict__ coT)
{
    __shared__ __align__(16) unsigned short Ub[32 * 400];
    const int t = threadIdx.x, lane = t & 63, w = t >> 6;
    const int l15 = lane & 15, quad = lane >> 4;
    const int b0 = blockIdx.x * 32;

    {
        int b = t >> 3, q = t & 7;
        const uint4* src = (const uint4*)(eR + (size_t)(b0 + b) * 128 + q * 16);
        uint4 v0 = src[0], v1 = src[1];
        uint4* dst = (uint4*)(Ub + b * 400 + q * 16);
        dst[0] = v0; dst[1] = v1;
    }
    for (int idx = t; idx < 8192; idx += 256) {
        int kk = idx >> 5, b = idx & 31;
        float v = (kk < 128) ? shB[(size_t)(b0 + b) * 128 + kk]
                             : soB[(size_t)(b0 + b) * 128 + kk - 128];
        Ub[b * 400 + 128 + kk] = f2b(v);
    }
    __syncthreads();

    const int mt = w >> 1, ntg = (w & 1) * 3;
    f32x4 acc[3];
    #pragma unroll
    for (int q = 0; q < 3; ++q) {
        float bias = bcat[(ntg + q) * 16 + l15];
        acc[q] = (f32x4){bias, bias, bias, bias};
    }
    #pragma unroll
    for (int ks = 0; ks < 12; ++ks) {
        bf16x8 a = *(const bf16x8*)(Ub + (mt * 16 + l15) * 400 + ks * 32 + quad * 8);
        #pragma unroll
        for (int q = 0; q < 3; ++q) {
            bf16x8 bw = *(const bf16x8*)(Wcatf + ((ks * 6 + ntg + q) * 64 + lane) * 8);
            acc[q] = __builtin_amdgcn_mfma_f32_16x16x32_bf16(a, bw, acc[q], 0, 0, 0);
        }
    }
    int brow = b0 + mt * 16 + quad * 4;
    #pragma unroll
    for (int q = 0; q < 3; ++q) {
        int n = (ntg + q) * 16 + l15;
        #pragma unroll
        for (int reg = 0; reg < 4; ++reg) {
            float v = acc[q][reg];
            int b = brow + reg;
            if (n < 32)      xrT[(size_t)n * BATCH + b] = f2b(fmaxf(v, 0.f));
            else if (n < 64) chT[(size_t)(n - 32) * BATCH + b] = v;
            else             coT[(size_t)(n - 64) * BATCH + b] = v;
        }
    }
}

// ---------------------------------------------------------------------------
// k_sM: s2[b][m] = sum_n relu(c[b][m] + t[b,n][m]); h and o merged.
// ---------------------------------------------------------------------------
__global__ __launch_bounds__(256) void k_sM(
    const unsigned short* __restrict__ tT_h, const unsigned short* __restrict__ tT_o,
    const float* __restrict__ chT, const float* __restrict__ coT,
    unsigned short* __restrict__ s2hT, unsigned short* __restrict__ s2oT)
{
    int bid = blockIdx.x;
    if (bid < 1024) {
        int gid = bid * 256 + threadIdx.x;
        int b = gid & (BATCH - 1), m = gid >> 13;
        const unsigned short* p = tT_h + (size_t)m * 163840 + b * 20;
        float c = chT[(size_t)m * BATCH + b];
        float s = 0.f;
        #pragma unroll
        for (int n = 0; n < 20; ++n) s += fmaxf(c + b2f(p[n]), 0.f);
        s2hT[(size_t)m * BATCH + b] = f2b(s);
    } else {
        int gid = (bid - 1024) * 256 + threadIdx.x;
        int b = gid & (BATCH - 1), m = gid >> 13;
        const unsigned short* p = tT_o + (size_t)m * 81920 + b * 10;
        float c = coT[(size_t)m * BATCH + b];
        float s = 0.f;
        #pragma unroll
        for (int n = 0; n < 10; ++n) s += fmaxf(c + b2f(p[n]), 0.f);
        s2oT[(size_t)m * BATCH + b] = f2b(s);
    }
}

// ---------------------------------------------------------------------------
// k_v: fused c2 + value-MLP via MFMA (verified). 32 b/block, 256 blocks.
// ---------------------------------------------------------------------------
__global__ __launch_bounds__(256) void k_v(
    const unsigned short* __restrict__ xrT, const unsigned short* __restrict__ s2hT,
    const unsigned short* __restrict__ s2oT,
    const unsigned short* __restrict__ Wc2f, const float* __restrict__ bc2,
    const unsigned short* __restrict__ vW0f, const float* __restrict__ vb0,
    const unsigned short* __restrict__ vW1f, const float* __restrict__ vb1,
    const float* __restrict__ vW2, const float* __restrict__ vb2,
    float* __restrict__ out)
{
    __shared__ __align__(16) unsigned short Vb[32 * 104];
    __shared__ __align__(16) unsigned short Hb[32 * 136];
    __shared__ __align__(16) unsigned short V1b[32 * 264];
    __shared__ __align__(16) float V2b[32 * 132];
    const int t = threadIdx.x, lane = t & 63, w = t >> 6;
    const int l15 = lane & 15, quad = lane >> 4;
    const int b0 = blockIdx.x * 32;
    const int mt = w >> 1, nh = w & 1;
    const int rowb = mt * 16 + quad * 4;

    for (int idx = t; idx < 32 * 96; idx += 256) {
        int k = idx >> 5, b = idx & 31;
        unsigned short v;
        if (k < 32)      v = xrT[(size_t)k * BATCH + b0 + b];
        else if (k < 64) v = s2hT[(size_t)(k - 32) * BATCH + b0 + b];
        else             v = s2oT[(size_t)(k - 64) * BATCH + b0 + b];
        Vb[b * 104 + k] = v;
    }
    __syncthreads();

    { // c2
        const int ntg = nh * 4;
        f32x4 acc[4];
        #pragma unroll
        for (int q = 0; q < 4; ++q) {
            float bias = bc2[(ntg + q) * 16 + l15];
            acc[q] = (f32x4){bias, bias, bias, bias};
        }
        #pragma unroll
        for (int ks = 0; ks < 3; ++ks) {
            bf16x8 a = *(const bf16x8*)(Vb + (mt * 16 + l15) * 104 + ks * 32 + quad * 8);
            #pragma unroll
            for (int q = 0; q < 4; ++q) {
                bf16x8 bw = *(const bf16x8*)(Wc2f + ((ks * 8 + ntg + q) * 64 + lane) * 8);
                acc[q] = __builtin_amdgcn_mfma_f32_16x16x32_bf16(a, bw, acc[q], 0, 0, 0);
            }
        }
        #pragma unroll
        for (int q = 0; q < 4; ++q)
            #pragma unroll
            for (int reg = 0; reg < 4; ++reg)
                Hb[(rowb + reg) * 136 + (ntg + q) * 16 + l15] = f2b(fmaxf(acc[q][reg], 0.f));
    }
    __syncthreads();

    { // v1
        const int ntg = nh * 8;
        f32x4 acc[8];
        #pragma unroll
        for (int q = 0; q < 8; ++q) {
            float bias = vb0[(ntg + q) * 16 + l15];
            acc[q] = (f32x4){bias, bias, bias, bias};
        }
        #pragma unroll
        for (int ks = 0; ks < 4; ++ks) {
            bf16x8 a = *(const bf16x8*)(Hb + (mt * 16 + l15) * 136 + ks * 32 + quad * 8);
            #pragma unroll
            for (int q = 0; q < 8; ++q) {
                bf16x8 bw = *(const bf16x8*)(vW0f + ((ks * 16 + ntg + q) * 64 + lane) * 8);
                acc[q] = __builtin_amdgcn_mfma_f32_16x16x32_bf16(a, bw, acc[q], 0, 0, 0);
            }
        }
        __syncthreads();
        #pragma unroll
        for (int q = 0; q < 8; ++q)
            #pragma unroll
            for (int reg = 0; reg < 4; ++reg)
                V1b[(rowb + reg) * 264 + (ntg + q) * 16 + l15] = f2b(fmaxf(acc[q][reg], 0.f));
    }
    __syncthreads();

    { // v2
        const int ntg = nh * 4;
        f32x4 acc[4];
        #pragma unroll
        for (int q = 0; q < 4; ++q) {
            float bias = vb1[(ntg + q) * 16 + l15];
            acc[q] = (f32x4){bias, bias, bias, bias};
        }
        #pragma unroll
        for (int ks = 0; ks < 8; ++ks) {
            bf16x8 a = *(const bf16x8*)(V1b + (mt * 16 + l15) * 264 + ks * 32 + quad * 8);
            #pragma unroll
            for (int q = 0; q < 4; ++q) {
                bf16x8 bw = *(const bf16x8*)(vW1f + ((ks * 8 + ntg + q) * 64 + lane) * 8);
                acc[q] = __builtin_amdgcn_mfma_f32_16x16x32_bf16(a, bw, acc[q], 0, 0, 0);
            }
        }
        #pragma unroll
        for (int q = 0; q < 4; ++q)
            #pragma unroll
            for (int reg = 0; reg < 4; ++reg)
                V2b[(rowb + reg) * 132 + (ntg + q) * 16 + l15] = fmaxf(acc[q][reg], 0.f);
    }
    __syncthreads();

    if (t < 32) {
        float acc = vb2[0];
        for (int k = 0; k < 128; ++k)
            acc = fmaf(V2b[t * 132 + k], vW2[k], acc);
        out[b0 + t] = acc;
    }
}

// ---------------------------------------------------------------------------
extern "C" void kernel_launch(void* const* d_in, const int* in_sizes, int n_in,
                              void* d_out, int out_size, void* d_ws, size_t ws_size,
                              hipStream_t stream)
{
    const float* state   = (const float*)d_in[0];
    const float* wr_W0   = (const float*)d_in[2];
    const float* wr_b0   = (const float*)d_in[3];
    const float* wr_W1   = (const float*)d_in[4];
    const float* wr_b1   = (const float*)d_in[5];
    const float* wh_W0   = (const float*)d_in[6];
    const float* wh_b0   = (const float*)d_in[7];
    const float* wh_W1   = (const float*)d_in[8];
    const float* wh_b1   = (const float*)d_in[9];
    const float* wo_W0   = (const float*)d_in[10];
    const float* wo_b0   = (const float*)d_in[11];
    const float* wo_W1   = (const float*)d_in[12];
    const float* wo_b1   = (const float*)d_in[13];
    const float* c1_relW = (const float*)d_in[14];
    const float* c1_relb = (const float*)d_in[15];
    const float* c1_rootW= (const float*)d_in[16];
    const float* c2_relW = (const float*)d_in[17];
    const float* c2_relb = (const float*)d_in[18];
    const float* c2_rootW= (const float*)d_in[19];
    const float* v_W0    = (const float*)d_in[20];
    const float* v_b0    = (const float*)d_in[21];
    const float* v_W1    = (const float*)d_in[22];
    const float* v_b1    = (const float*)d_in[23];
    const float* v_W2    = (const float*)d_in[24];
    const float* v_b2    = (const float*)d_in[25];

    char* ws = (char*)d_ws;
    size_t off = 0;
    auto alloc = [&](size_t bytes) -> char* {
        char* p = ws + off;
        off = (off + bytes + 255) & ~(size_t)255;
        return p;
    };
    float* shB  = (float*)alloc((size_t)BATCH * 128 * 4);          // b-major sums
    float* soB  = (float*)alloc((size_t)BATCH * 128 * 4);          // contiguous with shB
    unsigned short* tT_h = (unsigned short*)alloc((size_t)32 * 163840 * 2);
    unsigned short* tT_o = (unsigned short*)alloc((size_t)32 * 81920 * 2);
    unsigned short* eR   = (unsigned short*)alloc((size_t)BATCH * 128 * 2);
    unsigned short* xrT  = (unsigned short*)alloc((size_t)32 * BATCH * 2);
    float* chT  = (float*)alloc((size_t)32 * BATCH * 4);
    float* coT  = (float*)alloc((size_t)32 * BATCH * 4);
    unsigned short* s2hT = (unsigned short*)alloc((size_t)32 * BATCH * 2);
    unsigned short* s2oT = (unsigned short*)alloc((size_t)32 * BATCH * 2);
    float* bcat = (float*)alloc(96 * 4);
    float* bc2  = (float*)alloc(128 * 4);
    unsigned short* W0b_h = (unsigned short*)alloc(2048 * 2);
    unsigned short* W0b_o = (unsigned short*)alloc(2048 * 2);
    unsigned short* W0b_r = (unsigned short*)alloc(2048 * 2);
    unsigned short* W1f_h = (unsigned short*)alloc(32768 * 2);
    unsigned short* W1f_o = (unsigned short*)alloc(32768 * 2);
    unsigned short* W1f_r = (unsigned short*)alloc(32768 * 2);
    unsigned short* Mf_h  = (unsigned short*)alloc(4096 * 2);
    unsigned short* Mf_o  = (unsigned short*)alloc(4096 * 2);
    unsigned short* Wcatf = (unsigned short*)alloc(36864 * 2);
    unsigned short* Wc2f  = (unsigned short*)alloc(12288 * 2);
    unsigned short* vW0f  = (unsigned short*)alloc(32768 * 2);
    unsigned short* vW1f  = (unsigned short*)alloc(32768 * 2);
    (void)ws_size; (void)in_sizes; (void)n_in; (void)out_size;

    hipMemsetAsync(shB, 0, (size_t)2 * BATCH * 128 * 4, stream);

    k_prep<<<256, 256, 0, stream>>>(c1_relW, c1_relb, c1_rootW, c2_relW, c2_relb, c2_rootW,
                                    wh_W0, wh_W1, wo_W0, wo_W1, wr_W0, wr_W1, v_W0, v_W1,
                                    bcat, bc2, W0b_h, W0b_o, W0b_r, W1f_h, W1f_o, W1f_r,
                                    Mf_h, Mf_o, Wcatf, Wc2f, vW0f, vW1f);

    k_mlpD<<<248, 512, 0, stream>>>(state,
                                    W0b_h, wh_b0, W1f_h, wh_b1, Mf_h, tT_h, shB,
                                    W0b_o, wo_b0, W1f_o, wo_b1, Mf_o, tT_o, soB,
                                    W0b_r, wr_b0, W1f_r, wr_b1, eR);
    k_u2<<<256, 256, 0, stream>>>(eR, shB, soB, Wcatf, bcat, xrT, chT, coT);
    k_sM<<<2048, 256, 0, stream>>>(tT_h, tT_o, chT, coT, s2hT, s2oT);
    k_v<<<256, 256, 0, stream>>>(xrT, s2hT, s2oT, Wc2f, bc2, vW0f, v_b0, vW1f, v_b1,
                                 v_W2, v_b2, (float*)d_out);
}

// Round 10
// 185.023 us; speedup vs baseline: 1.7944x; 1.0420x over previous
//
#include <hip/hip_runtime.h>
#include <hip/hip_bf16.h>
#include <stdint.h>

#define BATCH 8192
#define NSTATE 30
#define DIN 13
#define E1 256
#define E2 128

typedef short bf16x8 __attribute__((ext_vector_type(8)));
typedef float f32x4 __attribute__((ext_vector_type(4)));

// f32 -> bf16 bits, round-to-nearest-even
__device__ __forceinline__ unsigned short f2b(float f) {
    unsigned u = __float_as_uint(f);
    u += 0x7FFFu + ((u >> 16) & 1u);
    return (unsigned short)(u >> 16);
}
__device__ __forceinline__ float b2f(unsigned short b) {
    return __uint_as_float((unsigned)b << 16);
}
__device__ __forceinline__ unsigned pack2(float a, float b) {     // relu+pack
    return ((unsigned)f2b(fmaxf(b, 0.f)) << 16) | f2b(fmaxf(a, 0.f));
}
__device__ __forceinline__ unsigned pack2n(float a, float b) {    // pack only
    return ((unsigned)f2b(b) << 16) | f2b(a);
}

// combined conv1 weight values (derived R1, verified)
__device__ __forceinline__ float wcat_val(int k, int m, const float* relW, const float* rootW) {
    int part = k >> 7, c = k & 127, grp = m >> 5, mm = m & 31;
    int off = c * 32 + mm;
    if (part == 0) return (grp == 0) ? rootW[4096 + off] + rootW[8192 + off]
                        : (grp == 1) ? relW[off] : relW[3*4096 + off];
    if (part == 1) return (grp == 0) ? relW[1*4096 + off]
                        : (grp == 1) ? relW[6*4096 + off] : relW[5*4096 + off];
    return (grp == 0) ? relW[2*4096 + off]
         : (grp == 1) ? relW[4*4096 + off] : relW[7*4096 + off];
}
__device__ __forceinline__ float wc2_val(int k, int n, const float* relW, const float* rootW) {
    int grp = k >> 5, kk = k & 31;
    int off = kk * 128 + n;
    if (grp == 0) return rootW[4096 + off] + rootW[8192 + off];
    if (grp == 1) return relW[4096 + off];
    return relW[8192 + off];
}

// ---------------------------------------------------------------------------
// k_prep: bias vectors + ALL bf16 MFMA fragment tables (verified decode):
//   entry i -> j=i&7, l=(i>>3)&63, k = ks*32+(l>>4)*8+j, n = nt*16+(l&15)
// ---------------------------------------------------------------------------
__global__ void k_prep(const float* __restrict__ c1_relW, const float* __restrict__ c1_relb,
                       const float* __restrict__ c1_rootW,
                       const float* __restrict__ c2_relW, const float* __restrict__ c2_relb,
                       const float* __restrict__ c2_rootW,
                       const float* __restrict__ wh_W0, const float* __restrict__ wh_W1,
                       const float* __restrict__ wo_W0, const float* __restrict__ wo_W1,
                       const float* __restrict__ wr_W0, const float* __restrict__ wr_W1,
                       const float* __restrict__ v_W0, const float* __restrict__ v_W1,
                       float* __restrict__ bcat, float* __restrict__ bc2,
                       unsigned short* __restrict__ W0b_h, unsigned short* __restrict__ W0b_o,
                       unsigned short* __restrict__ W0b_r,
                       unsigned short* __restrict__ W1f_h, unsigned short* __restrict__ W1f_o,
                       unsigned short* __restrict__ W1f_r,
                       unsigned short* __restrict__ Mf_h, unsigned short* __restrict__ Mf_o,
                       unsigned short* __restrict__ Wcatf, unsigned short* __restrict__ Wc2f,
                       unsigned short* __restrict__ vW0f, unsigned short* __restrict__ vW1f)
{
    int gid = blockIdx.x * blockDim.x + threadIdx.x;
    int gsz = gridDim.x * blockDim.x;

    for (int i = gid; i < 96; i += gsz) {
        int grp = i >> 5, mm = i & 31;
        float v;
        if (grp == 0)      v = c1_relb[32 + mm] + c1_relb[64 + mm];
        else if (grp == 1) v = c1_relb[mm] + c1_relb[128 + mm] + c1_relb[192 + mm];
        else               v = c1_relb[96 + mm] + c1_relb[160 + mm] + c1_relb[224 + mm];
        bcat[i] = v;
    }
    for (int i = gid; i < 128; i += gsz) bc2[i] = c2_relb[128 + i] + c2_relb[256 + i];

    for (int i = gid; i < 2048; i += gsz) {
        int n = i >> 3, j = i & 7;
        W0b_h[i] = (j < 7) ? f2b(wh_W0[j * 256 + n]) : 0;
        W0b_o[i] = (j < 7) ? f2b(wo_W0[j * 256 + n]) : 0;
        W0b_r[i] = (j < 6) ? f2b(wr_W0[j * 256 + n]) : 0;
    }
    for (int i = gid; i < 32768; i += gsz) {
        int j = i & 7, l = (i >> 3) & 63, nt = (i >> 9) & 7, ks = i >> 12;
        int k = ks * 32 + (l >> 4) * 8 + j;
        int n = nt * 16 + (l & 15);
        W1f_h[i] = f2b(wh_W1[k * 128 + n]);
        W1f_o[i] = f2b(wo_W1[k * 128 + n]);
        W1f_r[i] = f2b(wr_W1[k * 128 + n]);
    }
    for (int i = gid; i < 4096; i += gsz) {
        int j = i & 7, l = (i >> 3) & 63, nt = (i >> 9) & 1, ks = i >> 10;
        int k = ks * 32 + (l >> 4) * 8 + j;
        int n = nt * 16 + (l & 15);
        int i0 = k * 32 + n;
        Mf_h[i] = f2b(c1_rootW[i0] + c1_rootW[4*4096 + i0] + c1_rootW[6*4096 + i0] - c1_relW[6*4096 + i0]);
        Mf_o[i] = f2b(c1_rootW[3*4096 + i0] + c1_rootW[5*4096 + i0] + c1_rootW[7*4096 + i0] - c1_relW[7*4096 + i0]);
    }
    for (int i = gid; i < 36864; i += gsz) {
        int j = i & 7, l = (i >> 3) & 63, rem = i >> 9;
        int nt = rem % 6, ks = rem / 6;
        int k = ks * 32 + (l >> 4) * 8 + j;
        int n = nt * 16 + (l & 15);
        Wcatf[i] = f2b(wcat_val(k, n, c1_relW, c1_rootW));
    }
    for (int i = gid; i < 12288; i += gsz) {
        int j = i & 7, l = (i >> 3) & 63, rem = i >> 9;
        int nt = rem & 7, ks = rem >> 3;
        int k = ks * 32 + (l >> 4) * 8 + j;
        int n = nt * 16 + (l & 15);
        Wc2f[i] = f2b(wc2_val(k, n, c2_relW, c2_rootW));
    }
    for (int i = gid; i < 32768; i += gsz) {
        int j = i & 7, l = (i >> 3) & 63, rem = i >> 9;
        int nt = rem & 15, ks = rem >> 4;
        int k = ks * 32 + (l >> 4) * 8 + j;
        int n = nt * 16 + (l & 15);
        vW0f[i] = f2b(v_W0[k * 256 + n]);
    }
    for (int i = gid; i < 32768; i += gsz) {
        int j = i & 7, l = (i >> 3) & 63, rem = i >> 9;
        int nt = rem & 7, ks = rem >> 3;
        int k = ks * 32 + (l >> 4) * 8 + j;
        int n = nt * 16 + (l & 15);
        vW1f[i] = f2b(v_W1[k * 128 + n]);
    }
}

// ---------------------------------------------------------------------------
// mlp_blockE: R9-verified barrier-free per-wave pipeline, wave-contiguous rows.
// CHANGE vs R9: t stored ROW-MAJOR tR[row][32] via SWAPPED t-MFMA
// (A=Mf frag, B=e frag -> D = (e@M)^T: lane holds t[row=l15][cols nt*16+quad*4..+3])
// so each row's 64B line is written by adjacent instructions (full-line merge).
// LDS: W0s@0 4KB | Mfs@4K 8KB | W1s@12K 64KB | hs@77824 8x8448B = 142KB.
// ---------------------------------------------------------------------------
#define SM_W0   0
#define SM_MF   4096
#define SM_W1   12288
#define SM_HS   77824
#define SM_SZ   (77824 + 8 * 16 * 264 * 2)

template<int NPB, int NODE0, int INOFF, int INDIM, bool TAIL>
__device__ __forceinline__ void mlp_blockE(
    int blkrow0, const float* __restrict__ state,
    const unsigned short* __restrict__ W0b_g, const float* __restrict__ b0,
    const unsigned short* __restrict__ W1f_g, const float* __restrict__ b1,
    const unsigned short* __restrict__ Mf_g,
    unsigned short* __restrict__ tR, float* __restrict__ sumB,
    unsigned short* __restrict__ eR, char* smem)
{
    unsigned short* W0s = (unsigned short*)(smem + SM_W0);
    unsigned short* Mfs = (unsigned short*)(smem + SM_MF);
    unsigned short* W1s = (unsigned short*)(smem + SM_W1);

    const int t = threadIdx.x;
    const int lane = t & 63;
    const int w = t >> 6;
    const int l15 = lane & 15;
    const int quad = lane >> 4;
    const int R0 = blkrow0 + w * 128;     // this wave's 128 contiguous rows
    unsigned short* hw = (unsigned short*)(smem + SM_HS) + w * (16 * 264); // [16][264]
    unsigned short* ew = hw;                                              // alias [16][136]

    // ---- one-time staging ----
    if (t < 256) ((uint4*)W0s)[t] = ((const uint4*)W0b_g)[t];
    #pragma unroll
    for (int i = 0; i < 8; ++i)
        ((uint4*)W1s)[t + 512 * i] = ((const uint4*)W1f_g)[t + 512 * i];
    if constexpr (TAIL)
        ((uint4*)Mfs)[t] = ((const uint4*)Mf_g)[t];

    f32x4 b0r[16], b1r[8];
    #pragma unroll
    for (int nt = 0; nt < 16; ++nt) {
        float4 bb = *(const float4*)(b0 + nt * 16 + quad * 4);
        b0r[nt] = (f32x4){bb.x, bb.y, bb.z, bb.w};
    }
    #pragma unroll
    for (int nt = 0; nt < 8; ++nt) {
        float4 bb = *(const float4*)(b1 + nt * 16 + quad * 4);
        b1r[nt] = (f32x4){bb.x, bb.y, bb.z, bb.w};
    }
    __syncthreads();   // the ONLY block-wide barrier

    float s0 = 0.f, s1 = 0.f;
    int bcur = R0 / NPB;

    for (int sub = 0; sub < 8; ++sub) {
        const int wrow0 = R0 + sub * 16;

        // ---- X: contiguous per-lane loads (quad0 lanes only) ----
        bf16x8 bx = {};
        if (quad == 0) {
            int grow = wrow0 + l15;
            int b = grow / NPB;
            int n = grow - b * NPB + NODE0;
            const float* xp = state + ((size_t)b * NSTATE + n) * DIN + INOFF;
            #pragma unroll
            for (int j = 0; j < INDIM; ++j)
                bx[j] = (short)f2b(xp[j]);
        }

        // ---- layer 1 (swapped): lane holds h[r=l15][n=nt*16+quad*4+reg] ----
        #pragma unroll
        for (int nt = 0; nt < 16; ++nt) {
            bf16x8 aw = {};
            if (quad == 0)
                aw = *(const bf16x8*)(W0s + (nt * 16 + l15) * 8);
            f32x4 c = b0r[nt];
            c = __builtin_amdgcn_mfma_f32_16x16x32_bf16(aw, bx, c, 0, 0, 0);
            uint2 pv = {pack2(c[0], c[1]), pack2(c[2], c[3])};
            *(uint2*)(hw + l15 * 264 + nt * 16 + quad * 4) = pv;
        }

        // ---- layer 2 (swapped): lane holds e[r=l15][n=nt*16+quad*4+reg] ----
        f32x4 acc[8];
        #pragma unroll
        for (int nt = 0; nt < 8; ++nt) acc[nt] = b1r[nt];
        #pragma unroll
        for (int ks = 0; ks < 8; ++ks) {
            bf16x8 bh = *(const bf16x8*)(hw + l15 * 264 + ks * 32 + quad * 8);
            #pragma unroll
            for (int nt = 0; nt < 8; ++nt) {
                bf16x8 aw = *(const bf16x8*)(W1s + ((ks * 8 + nt) * 64 + lane) * 8);
                acc[nt] = __builtin_amdgcn_mfma_f32_16x16x32_bf16(aw, bh, acc[nt], 0, 0, 0);
            }
        }

        if constexpr (TAIL) {
            // intra-wave WAR: hs reads complete before ew overwrite
            __asm__ __volatile__("s_waitcnt lgkmcnt(0)" ::: "memory");
            #pragma unroll
            for (int nt = 0; nt < 8; ++nt) {
                uint2 pv = {pack2(acc[nt][0], acc[nt][1]), pack2(acc[nt][2], acc[nt][3])};
                *(uint2*)(ew + l15 * 136 + nt * 16 + quad * 4) = pv;
            }

            // t = e @ M, SWAPPED (A=Mf frag, B=e frag) -> D=(e@M)^T:
            // lane holds t[row=wrow0+l15][cols nt*16+quad*4 .. +3]
            f32x4 tacc[2] = {{0.f,0.f,0.f,0.f},{0.f,0.f,0.f,0.f}};
            #pragma unroll
            for (int ks = 0; ks < 4; ++ks) {
                bf16x8 ae = *(const bf16x8*)(ew + l15 * 136 + ks * 32 + quad * 8);
                #pragma unroll
                for (int nt = 0; nt < 2; ++nt) {
                    bf16x8 bm = *(const bf16x8*)(Mfs + ((ks * 2 + nt) * 64 + lane) * 8);
                    tacc[nt] = __builtin_amdgcn_mfma_f32_16x16x32_bf16(bm, ae, tacc[nt], 0, 0, 0);
                }
            }
            #pragma unroll
            for (int nt = 0; nt < 2; ++nt) {
                uint2 pv = {pack2n(tacc[nt][0], tacc[nt][1]), pack2n(tacc[nt][2], tacc[nt][3])};
                *(uint2*)(tR + (size_t)(wrow0 + l15) * 32 + nt * 16 + quad * 4) = pv;
            }

            // per-b sums in registers (cols 2*lane, 2*lane+1); flush at b bounds
            #pragma unroll
            for (int r = 0; r < 16; ++r) {
                int b = (wrow0 + r) / NPB;
                if (b != bcur) {
                    bool interior = (bcur * NPB >= R0) && ((bcur + 1) * NPB <= R0 + 128);
                    float* dst = sumB + (size_t)bcur * 128 + 2 * lane;
                    if (interior) { dst[0] = s0; dst[1] = s1; }
                    else { atomicAdd(dst, s0); atomicAdd(dst + 1, s1); }
                    s0 = 0.f; s1 = 0.f; bcur = b;
                }
                unsigned v = *(const unsigned*)(ew + r * 136 + lane * 2);
                s0 += b2f((unsigned short)v);
                s1 += b2f((unsigned short)(v >> 16));
            }
            if (sub == 7) {
                bool interior = (bcur * NPB >= R0) && ((bcur + 1) * NPB <= R0 + 128);
                float* dst = sumB + (size_t)bcur * 128 + 2 * lane;
                if (interior) { dst[0] = s0; dst[1] = s1; }
                else { atomicAdd(dst, s0); atomicAdd(dst + 1, s1); }
            }
        } else {
            // root: direct row-major global store eR[row][n]
            #pragma unroll
            for (int nt = 0; nt < 8; ++nt) {
                uint2 pv = {pack2(acc[nt][0], acc[nt][1]), pack2(acc[nt][2], acc[nt][3])};
                *(uint2*)(eR + (size_t)(wrow0 + l15) * 128 + nt * 16 + quad * 4) = pv;
            }
        }
        __asm__ __volatile__("" ::: "memory");   // keep iteration LDS order
    }
}

__global__ __launch_bounds__(512, 2) void k_mlpE(
    const float* __restrict__ state,
    const unsigned short* __restrict__ W0b_h, const float* __restrict__ b0_h,
    const unsigned short* __restrict__ W1f_h, const float* __restrict__ b1_h,
    const unsigned short* __restrict__ Mf_h, unsigned short* __restrict__ tR_h,
    float* __restrict__ shB,
    const unsigned short* __restrict__ W0b_o, const float* __restrict__ b0_o,
    const unsigned short* __restrict__ W1f_o, const float* __restrict__ b1_o,
    const unsigned short* __restrict__ Mf_o, unsigned short* __restrict__ tR_o,
    float* __restrict__ soB,
    const unsigned short* __restrict__ W0b_r, const float* __restrict__ b0_r,
    const unsigned short* __restrict__ W1f_r, const float* __restrict__ b1_r,
    unsigned short* __restrict__ eR)
{
    __shared__ __align__(16) char smem[SM_SZ];
    int bid = blockIdx.x;
    if (bid < 160)
        mlp_blockE<20, 0, 6, 7, true>(bid * 1024, state, W0b_h, b0_h, W1f_h, b1_h,
                                      Mf_h, tR_h, shB, nullptr, smem);
    else if (bid < 240)
        mlp_blockE<10, 20, 6, 7, true>((bid - 160) * 1024, state, W0b_o, b0_o, W1f_o, b1_o,
                                       Mf_o, tR_o, soB, nullptr, smem);
    else
        mlp_blockE<1, 0, 0, 6, false>((bid - 240) * 1024, state, W0b_r, b0_r, W1f_r, b1_r,
                                      nullptr, nullptr, nullptr, eR, smem);
}

// ---------------------------------------------------------------------------
// k_tail: FUSED u2 + sM + v. Per 32-b block (256 thr, 4 waves):
//   1) stage U = [er | sh | so] (row-major)            2) U-MFMA -> xr,ch,co
//   3) t-scan (row-major tR, coalesced) -> s2h,s2o     4) c2 -> v1 -> v2 -> v3
// LDS 66KB -> 2 blocks/CU. V1b aliases Ub (dead after phase 2).
// ---------------------------------------------------------------------------
__global__ __launch_bounds__(256, 2) void k_tail(
    const unsigned short* __restrict__ eR,
    const float* __restrict__ shB, const float* __restrict__ soB,
    const unsigned short* __restrict__ tR_h, const unsigned short* __restrict__ tR_o,
    const unsigned short* __restrict__ Wcatf, const float* __restrict__ bcat,
    const unsigned short* __restrict__ Wc2f, const float* __restrict__ bc2,
    const unsigned short* __restrict__ vW0f, const float* __restrict__ vb0,
    const unsigned short* __restrict__ vW1f, const float* __restrict__ vb1,
    const float* __restrict__ vW2, const float* __restrict__ vb2,
    float* __restrict__ out)
{
    __shared__ __align__(16) char sm[66048];
    unsigned short* Ub  = (unsigned short*)(sm);          // [32][400]
    unsigned short* V1b = (unsigned short*)(sm);          // alias  [32][264]
    unsigned short* Vb  = (unsigned short*)(sm + 25600);  // [32][104]
    float* chL          = (float*)(sm + 32256);           // [32][32]
    float* coL          = (float*)(sm + 36352);           // [32][32]
    unsigned short* Hb  = (unsigned short*)(sm + 40448);  // [32][136]
    float* V2b          = (float*)(sm + 49152);           // [32][132]

    const int t = threadIdx.x, lane = t & 63, w = t >> 6;
    const int l15 = lane & 15, quad = lane >> 4;
    const int b0 = blockIdx.x * 32;
    const int mt = w >> 1, nh = w & 1;
    const int rowb = mt * 16 + quad * 4;

    // ---- phase 1: stage U ----
    {
        int b = t >> 3, q = t & 7;
        const uint4* src = (const uint4*)(eR + (size_t)(b0 + b) * 128 + q * 16);
        uint4 v0 = src[0], v1 = src[1];
        uint4* dst = (uint4*)(Ub + b * 400 + q * 16);
        dst[0] = v0; dst[1] = v1;
    }
    for (int idx = t; idx < 8192; idx += 256) {
        int kk = idx >> 5, b = idx & 31;
        float v = (kk < 128) ? shB[(size_t)(b0 + b) * 128 + kk]
                             : soB[(size_t)(b0 + b) * 128 + kk - 128];
        Ub[b * 400 + 128 + kk] = f2b(v);
    }
    __syncthreads();

    // ---- phase 2: U-MFMA (unswapped, verified): xr / ch / co ----
    {
        const int ntg = nh * 3;
        f32x4 acc[3];
        #pragma unroll
        for (int q = 0; q < 3; ++q) {
            float bias = bcat[(ntg + q) * 16 + l15];
            acc[q] = (f32x4){bias, bias, bias, bias};
        }
        #pragma unroll
        for (int ks = 0; ks < 12; ++ks) {
            bf16x8 a = *(const bf16x8*)(Ub + (mt * 16 + l15) * 400 + ks * 32 + quad * 8);
            #pragma unroll
            for (int q = 0; q < 3; ++q) {
                bf16x8 bw = *(const bf16x8*)(Wcatf + ((ks * 6 + ntg + q) * 64 + lane) * 8);
                acc[q] = __builtin_amdgcn_mfma_f32_16x16x32_bf16(a, bw, acc[q], 0, 0, 0);
            }
        }
        #pragma unroll
        for (int q = 0; q < 3; ++q) {
            int n = (ntg + q) * 16 + l15;
            #pragma unroll
            for (int reg = 0; reg < 4; ++reg) {
                float v = acc[q][reg];
                int b = mt * 16 + quad * 4 + reg;
                if (n < 32)      Vb[b * 104 + n] = f2b(fmaxf(v, 0.f));
                else if (n < 64) chL[b * 32 + (n - 32)] = v;
                else             coL[b * 32 + (n - 64)] = v;
            }
        }
    }
    __syncthreads();

    // ---- phase 3: t-scan -> s2h, s2o ----
    for (int idx = t; idx < 1024; idx += 256) {
        int b = idx >> 5, m = idx & 31;
        float ch = chL[b * 32 + m];
        const unsigned short* p = tR_h + (size_t)(b0 + b) * 20 * 32 + m;
        float s = 0.f;
        #pragma unroll
        for (int n = 0; n < 20; ++n) s += fmaxf(ch + b2f(p[n * 32]), 0.f);
        Vb[b * 104 + 32 + m] = f2b(s);
        float co = coL[b * 32 + m];
        const unsigned short* p2 = tR_o + (size_t)(b0 + b) * 10 * 32 + m;
        float s2 = 0.f;
        #pragma unroll
        for (int n = 0; n < 10; ++n) s2 += fmaxf(co + b2f(p2[n * 32]), 0.f);
        Vb[b * 104 + 64 + m] = f2b(s2);
    }
    __syncthreads();

    // ---- phase 4: c2 ----
    {
        const int ntg = nh * 4;
        f32x4 acc[4];
        #pragma unroll
        for (int q = 0; q < 4; ++q) {
            float bias = bc2[(ntg + q) * 16 + l15];
            acc[q] = (f32x4){bias, bias, bias, bias};
        }
        #pragma unroll
        for (int ks = 0; ks < 3; ++ks) {
            bf16x8 a = *(const bf16x8*)(Vb + (mt * 16 + l15) * 104 + ks * 32 + quad * 8);
            #pragma unroll
            for (int q = 0; q < 4; ++q) {
                bf16x8 bw = *(const bf16x8*)(Wc2f + ((ks * 8 + ntg + q) * 64 + lane) * 8);
                acc[q] = __builtin_amdgcn_mfma_f32_16x16x32_bf16(a, bw, acc[q], 0, 0, 0);
            }
        }
        #pragma unroll
        for (int q = 0; q < 4; ++q)
            #pragma unroll
            for (int reg = 0; reg < 4; ++reg)
                Hb[(rowb + reg) * 136 + (ntg + q) * 16 + l15] = f2b(fmaxf(acc[q][reg], 0.f));
    }
    __syncthreads();

    // ---- phase 5: v1 (writes V1b, aliases dead Ub) ----
    {
        const int ntg = nh * 8;
        f32x4 acc[8];
        #pragma unroll
        for (int q = 0; q < 8; ++q) {
            float bias = vb0[(ntg + q) * 16 + l15];
            acc[q] = (f32x4){bias, bias, bias, bias};
        }
        #pragma unroll
        for (int ks = 0; ks < 4; ++ks) {
            bf16x8 a = *(const bf16x8*)(Hb + (mt * 16 + l15) * 136 + ks * 32 + quad * 8);
            #pragma unroll
            for (int q = 0; q < 8; ++q) {
                bf16x8 bw = *(const bf16x8*)(vW0f + ((ks * 16 + ntg + q) * 64 + lane) * 8);
                acc[q] = __builtin_amdgcn_mfma_f32_16x16x32_bf16(a, bw, acc[q], 0, 0, 0);
            }
        }
        #pragma unroll
        for (int q = 0; q < 8; ++q)
            #pragma unroll
            for (int reg = 0; reg < 4; ++reg)
                V1b[(rowb + reg) * 264 + (ntg + q) * 16 + l15] = f2b(fmaxf(acc[q][reg], 0.f));
    }
    __syncthreads();

    // ---- phase 6: v2 ----
    {
        const int ntg = nh * 4;
        f32x4 acc[4];
        #pragma unroll
        for (int q = 0; q < 4; ++q) {
            float bias = vb1[(ntg + q) * 16 + l15];
            acc[q] = (f32x4){bias, bias, bias, bias};
        }
        #pragma unroll
        for (int ks = 0; ks < 8; ++ks) {
            bf16x8 a = *(const bf16x8*)(V1b + (mt * 16 + l15) * 264 + ks * 32 + quad * 8);
            #pragma unroll
            for (int q = 0; q < 4; ++q) {
                bf16x8 bw = *(const bf16x8*)(vW1f + ((ks * 8 + ntg + q) * 64 + lane) * 8);
                acc[q] = __builtin_amdgcn_mfma_f32_16x16x32_bf16(a, bw, acc[q], 0, 0, 0);
            }
        }
        #pragma unroll
        for (int q = 0; q < 4; ++q)
            #pragma unroll
            for (int reg = 0; reg < 4; ++reg)
                V2b[(rowb + reg) * 132 + (ntg + q) * 16 + l15] = fmaxf(acc[q][reg], 0.f);
    }
    __syncthreads();

    // ---- phase 7: v3, 8 threads per b + shuffle reduce ----
    {
        int b = t >> 3, j = t & 7;
        float v = 0.f;
        #pragma unroll
        for (int k = 0; k < 16; ++k)
            v = fmaf(V2b[b * 132 + j * 16 + k], vW2[j * 16 + k], v);
        v += __shfl_down(v, 4, 8);
        v += __shfl_down(v, 2, 8);
        v += __shfl_down(v, 1, 8);
        if (j == 0) out[b0 + b] = v + vb2[0];
    }
}

// ---------------------------------------------------------------------------
extern "C" void kernel_launch(void* const* d_in, const int* in_sizes, int n_in,
                              void* d_out, int out_size, void* d_ws, size_t ws_size,
                              hipStream_t stream)
{
    const float* state   = (const float*)d_in[0];
    const float* wr_W0   = (const float*)d_in[2];
    const float* wr_b0   = (const float*)d_in[3];
    const float* wr_W1   = (const float*)d_in[4];
    const float* wr_b1   = (const float*)d_in[5];
    const float* wh_W0   = (const float*)d_in[6];
    const float* wh_b0   = (const float*)d_in[7];
    const float* wh_W1   = (const float*)d_in[8];
    const float* wh_b1   = (const float*)d_in[9];
    const float* wo_W0   = (const float*)d_in[10];
    const float* wo_b0   = (const float*)d_in[11];
    const float* wo_W1   = (const float*)d_in[12];
    const float* wo_b1   = (const float*)d_in[13];
    const float* c1_relW = (const float*)d_in[14];
    const float* c1_relb = (const float*)d_in[15];
    const float* c1_rootW= (const float*)d_in[16];
    const float* c2_relW = (const float*)d_in[17];
    const float* c2_relb = (const float*)d_in[18];
    const float* c2_rootW= (const float*)d_in[19];
    const float* v_W0    = (const float*)d_in[20];
    const float* v_b0    = (const float*)d_in[21];
    const float* v_W1    = (const float*)d_in[22];
    const float* v_b1    = (const float*)d_in[23];
    const float* v_W2    = (const float*)d_in[24];
    const float* v_b2    = (const float*)d_in[25];

    char* ws = (char*)d_ws;
    size_t off = 0;
    auto alloc = [&](size_t bytes) -> char* {
        char* p = ws + off;
        off = (off + bytes + 255) & ~(size_t)255;
        return p;
    };
    float* shB  = (float*)alloc((size_t)BATCH * 128 * 4);          // b-major sums
    float* soB  = (float*)alloc((size_t)BATCH * 128 * 4);          // contiguous with shB
    unsigned short* tR_h = (unsigned short*)alloc((size_t)163840 * 32 * 2);  // row-major
    unsigned short* tR_o = (unsigned short*)alloc((size_t)81920 * 32 * 2);   // row-major
    unsigned short* eR   = (unsigned short*)alloc((size_t)BATCH * 128 * 2);
    float* bcat = (float*)alloc(96 * 4);
    float* bc2  = (float*)alloc(128 * 4);
    unsigned short* W0b_h = (unsigned short*)alloc(2048 * 2);
    unsigned short* W0b_o = (unsigned short*)alloc(2048 * 2);
    unsigned short* W0b_r = (unsigned short*)alloc(2048 * 2);
    unsigned short* W1f_h = (unsigned short*)alloc(32768 * 2);
    unsigned short* W1f_o = (unsigned short*)alloc(32768 * 2);
    unsigned short* W1f_r = (unsigned short*)alloc(32768 * 2);
    unsigned short* Mf_h  = (unsigned short*)alloc(4096 * 2);
    unsigned short* Mf_o  = (unsigned short*)alloc(4096 * 2);
    unsigned short* Wcatf = (unsigned short*)alloc(36864 * 2);
    unsigned short* Wc2f  = (unsigned short*)alloc(12288 * 2);
    unsigned short* vW0f  = (unsigned short*)alloc(32768 * 2);
    unsigned short* vW1f  = (unsigned short*)alloc(32768 * 2);
    (void)ws_size; (void)in_sizes; (void)n_in; (void)out_size;

    hipMemsetAsync(shB, 0, (size_t)2 * BATCH * 128 * 4, stream);

    k_prep<<<256, 256, 0, stream>>>(c1_relW, c1_relb, c1_rootW, c2_relW, c2_relb, c2_rootW,
                                    wh_W0, wh_W1, wo_W0, wo_W1, wr_W0, wr_W1, v_W0, v_W1,
                                    bcat, bc2, W0b_h, W0b_o, W0b_r, W1f_h, W1f_o, W1f_r,
                                    Mf_h, Mf_o, Wcatf, Wc2f, vW0f, vW1f);

    k_mlpE<<<248, 512, 0, stream>>>(state,
                                    W0b_h, wh_b0, W1f_h, wh_b1, Mf_h, tR_h, shB,
                                    W0b_o, wo_b0, W1f_o, wo_b1, Mf_o, tR_o, soB,
                                    W0b_r, wr_b0, W1f_r, wr_b1, eR);

    k_tail<<<256, 256, 0, stream>>>(eR, shB, soB, tR_h, tR_o,
                                    Wcatf, bcat, Wc2f, bc2, vW0f, v_b0, vW1f, v_b1,
                                    v_W2, v_b2, (float*)d_out);
}

// Round 11
// 173.659 us; speedup vs baseline: 1.9118x; 1.0654x over previous
//
#include <hip/hip_runtime.h>
#include <hip/hip_bf16.h>
#include <stdint.h>

#define BATCH 8192
#define NSTATE 30
#define DIN 13
#define E1 256
#define E2 128

typedef short bf16x8 __attribute__((ext_vector_type(8)));
typedef float f32x4 __attribute__((ext_vector_type(4)));

// f32 -> bf16 bits, round-to-nearest-even
__device__ __forceinline__ unsigned short f2b(float f) {
    unsigned u = __float_as_uint(f);
    u += 0x7FFFu + ((u >> 16) & 1u);
    return (unsigned short)(u >> 16);
}
__device__ __forceinline__ float b2f(unsigned short b) {
    return __uint_as_float((unsigned)b << 16);
}
__device__ __forceinline__ unsigned pack2(float a, float b) {     // relu+pack
    return ((unsigned)f2b(fmaxf(b, 0.f)) << 16) | f2b(fmaxf(a, 0.f));
}
__device__ __forceinline__ unsigned pack2n(float a, float b) {    // pack only
    return ((unsigned)f2b(b) << 16) | f2b(a);
}

// combined conv1 weight values (derived R1, verified)
__device__ __forceinline__ float wcat_val(int k, int m, const float* relW, const float* rootW) {
    int part = k >> 7, c = k & 127, grp = m >> 5, mm = m & 31;
    int off = c * 32 + mm;
    if (part == 0) return (grp == 0) ? rootW[4096 + off] + rootW[8192 + off]
                        : (grp == 1) ? relW[off] : relW[3*4096 + off];
    if (part == 1) return (grp == 0) ? relW[1*4096 + off]
                        : (grp == 1) ? relW[6*4096 + off] : relW[5*4096 + off];
    return (grp == 0) ? relW[2*4096 + off]
         : (grp == 1) ? relW[4*4096 + off] : relW[7*4096 + off];
}
__device__ __forceinline__ float wc2_val(int k, int n, const float* relW, const float* rootW) {
    int grp = k >> 5, kk = k & 31;
    int off = kk * 128 + n;
    if (grp == 0) return rootW[4096 + off] + rootW[8192 + off];
    if (grp == 1) return relW[4096 + off];
    return relW[8192 + off];
}

// ---------------------------------------------------------------------------
// k_prep: bias vectors + ALL bf16 MFMA fragment tables (verified decode):
//   entry i -> j=i&7, l=(i>>3)&63, k = ks*32+(l>>4)*8+j, n = nt*16+(l&15)
// ---------------------------------------------------------------------------
__global__ void k_prep(const float* __restrict__ c1_relW, const float* __restrict__ c1_relb,
                       const float* __restrict__ c1_rootW,
                       const float* __restrict__ c2_relW, const float* __restrict__ c2_relb,
                       const float* __restrict__ c2_rootW,
                       const float* __restrict__ wh_W0, const float* __restrict__ wh_W1,
                       const float* __restrict__ wo_W0, const float* __restrict__ wo_W1,
                       const float* __restrict__ wr_W0, const float* __restrict__ wr_W1,
                       const float* __restrict__ v_W0, const float* __restrict__ v_W1,
                       float* __restrict__ bcat, float* __restrict__ bc2,
                       unsigned short* __restrict__ W0b_h, unsigned short* __restrict__ W0b_o,
                       unsigned short* __restrict__ W0b_r,
                       unsigned short* __restrict__ W1f_h, unsigned short* __restrict__ W1f_o,
                       unsigned short* __restrict__ W1f_r,
                       unsigned short* __restrict__ Mf_h, unsigned short* __restrict__ Mf_o,
                       unsigned short* __restrict__ Wcatf, unsigned short* __restrict__ Wc2f,
                       unsigned short* __restrict__ vW0f, unsigned short* __restrict__ vW1f)
{
    int gid = blockIdx.x * blockDim.x + threadIdx.x;
    int gsz = gridDim.x * blockDim.x;

    for (int i = gid; i < 96; i += gsz) {
        int grp = i >> 5, mm = i & 31;
        float v;
        if (grp == 0)      v = c1_relb[32 + mm] + c1_relb[64 + mm];
        else if (grp == 1) v = c1_relb[mm] + c1_relb[128 + mm] + c1_relb[192 + mm];
        else               v = c1_relb[96 + mm] + c1_relb[160 + mm] + c1_relb[224 + mm];
        bcat[i] = v;
    }
    for (int i = gid; i < 128; i += gsz) bc2[i] = c2_relb[128 + i] + c2_relb[256 + i];

    for (int i = gid; i < 2048; i += gsz) {
        int n = i >> 3, j = i & 7;
        W0b_h[i] = (j < 7) ? f2b(wh_W0[j * 256 + n]) : 0;
        W0b_o[i] = (j < 7) ? f2b(wo_W0[j * 256 + n]) : 0;
        W0b_r[i] = (j < 6) ? f2b(wr_W0[j * 256 + n]) : 0;
    }
    for (int i = gid; i < 32768; i += gsz) {
        int j = i & 7, l = (i >> 3) & 63, nt = (i >> 9) & 7, ks = i >> 12;
        int k = ks * 32 + (l >> 4) * 8 + j;
        int n = nt * 16 + (l & 15);
        W1f_h[i] = f2b(wh_W1[k * 128 + n]);
        W1f_o[i] = f2b(wo_W1[k * 128 + n]);
        W1f_r[i] = f2b(wr_W1[k * 128 + n]);
    }
    for (int i = gid; i < 4096; i += gsz) {
        int j = i & 7, l = (i >> 3) & 63, nt = (i >> 9) & 1, ks = i >> 10;
        int k = ks * 32 + (l >> 4) * 8 + j;
        int n = nt * 16 + (l & 15);
        int i0 = k * 32 + n;
        Mf_h[i] = f2b(c1_rootW[i0] + c1_rootW[4*4096 + i0] + c1_rootW[6*4096 + i0] - c1_relW[6*4096 + i0]);
        Mf_o[i] = f2b(c1_rootW[3*4096 + i0] + c1_rootW[5*4096 + i0] + c1_rootW[7*4096 + i0] - c1_relW[7*4096 + i0]);
    }
    for (int i = gid; i < 36864; i += gsz) {
        int j = i & 7, l = (i >> 3) & 63, rem = i >> 9;
        int nt = rem % 6, ks = rem / 6;
        int k = ks * 32 + (l >> 4) * 8 + j;
        int n = nt * 16 + (l & 15);
        Wcatf[i] = f2b(wcat_val(k, n, c1_relW, c1_rootW));
    }
    for (int i = gid; i < 12288; i += gsz) {
        int j = i & 7, l = (i >> 3) & 63, rem = i >> 9;
        int nt = rem & 7, ks = rem >> 3;
        int k = ks * 32 + (l >> 4) * 8 + j;
        int n = nt * 16 + (l & 15);
        Wc2f[i] = f2b(wc2_val(k, n, c2_relW, c2_rootW));
    }
    for (int i = gid; i < 32768; i += gsz) {
        int j = i & 7, l = (i >> 3) & 63, rem = i >> 9;
        int nt = rem & 15, ks = rem >> 4;
        int k = ks * 32 + (l >> 4) * 8 + j;
        int n = nt * 16 + (l & 15);
        vW0f[i] = f2b(v_W0[k * 256 + n]);
    }
    for (int i = gid; i < 32768; i += gsz) {
        int j = i & 7, l = (i >> 3) & 63, rem = i >> 9;
        int nt = rem & 7, ks = rem >> 3;
        int k = ks * 32 + (l >> 4) * 8 + j;
        int n = nt * 16 + (l & 15);
        vW1f[i] = f2b(v_W1[k * 128 + n]);
    }
}

// ---------------------------------------------------------------------------
// mlp_blockE: R9/R10-verified barrier-free per-wave pipeline.
// CHANGE vs R10: biases live in LDS (1.5 KB), not 96 VGPRs of registers —
// frees the register file for fragment prefetch pipelining.
// LDS: W0s@0 4K | Mfs@4K 8K | W1s@12K 64K | b0s@77824 1K | b1s@78848 0.5K |
//      hs@79360 8x8448 = 143.5K total.
// ---------------------------------------------------------------------------
#define SM_W0   0
#define SM_MF   4096
#define SM_W1   12288
#define SM_B0   77824
#define SM_B1   78848
#define SM_HS   79360
#define SM_SZ   (79360 + 8 * 16 * 264 * 2)

template<int NPB, int NODE0, int INOFF, int INDIM, bool TAIL>
__device__ __forceinline__ void mlp_blockE(
    int blkrow0, const float* __restrict__ state,
    const unsigned short* __restrict__ W0b_g, const float* __restrict__ b0,
    const unsigned short* __restrict__ W1f_g, const float* __restrict__ b1,
    const unsigned short* __restrict__ Mf_g,
    unsigned short* __restrict__ tR, float* __restrict__ sumB,
    unsigned short* __restrict__ eR, char* smem)
{
    unsigned short* W0s = (unsigned short*)(smem + SM_W0);
    unsigned short* Mfs = (unsigned short*)(smem + SM_MF);
    unsigned short* W1s = (unsigned short*)(smem + SM_W1);
    float* b0s          = (float*)(smem + SM_B0);
    float* b1s          = (float*)(smem + SM_B1);

    const int t = threadIdx.x;
    const int lane = t & 63;
    const int w = t >> 6;
    const int l15 = lane & 15;
    const int quad = lane >> 4;
    const int R0 = blkrow0 + w * 128;     // this wave's 128 contiguous rows
    unsigned short* hw = (unsigned short*)(smem + SM_HS) + w * (16 * 264); // [16][264]
    unsigned short* ew = hw;                                              // alias [16][136]

    // ---- one-time staging ----
    if (t < 256) { ((uint4*)W0s)[t] = ((const uint4*)W0b_g)[t]; b0s[t] = b0[t]; }
    if (t >= 256 && t < 384) b1s[t - 256] = b1[t - 256];
    #pragma unroll
    for (int i = 0; i < 8; ++i)
        ((uint4*)W1s)[t + 512 * i] = ((const uint4*)W1f_g)[t + 512 * i];
    if constexpr (TAIL)
        ((uint4*)Mfs)[t] = ((const uint4*)Mf_g)[t];
    __syncthreads();   // the ONLY block-wide barrier

    float s0 = 0.f, s1 = 0.f;
    int bcur = R0 / NPB;

    for (int sub = 0; sub < 8; ++sub) {
        const int wrow0 = R0 + sub * 16;

        // ---- X: contiguous per-lane loads (quad0 lanes only) ----
        bf16x8 bx = {};
        if (quad == 0) {
            int grow = wrow0 + l15;
            int b = grow / NPB;
            int n = grow - b * NPB + NODE0;
            const float* xp = state + ((size_t)b * NSTATE + n) * DIN + INOFF;
            #pragma unroll
            for (int j = 0; j < INDIM; ++j)
                bx[j] = (short)f2b(xp[j]);
        }

        // ---- layer 1 (swapped): lane holds h[r=l15][n=nt*16+quad*4+reg] ----
        #pragma unroll
        for (int nt = 0; nt < 16; ++nt) {
            bf16x8 aw = {};
            if (quad == 0)
                aw = *(const bf16x8*)(W0s + (nt * 16 + l15) * 8);
            float4 bb = *(const float4*)(b0s + nt * 16 + quad * 4);
            f32x4 c = {bb.x, bb.y, bb.z, bb.w};
            c = __builtin_amdgcn_mfma_f32_16x16x32_bf16(aw, bx, c, 0, 0, 0);
            uint2 pv = {pack2(c[0], c[1]), pack2(c[2], c[3])};
            *(uint2*)(hw + l15 * 264 + nt * 16 + quad * 4) = pv;
        }

        // ---- layer 2 (swapped): lane holds e[r=l15][n=nt*16+quad*4+reg] ----
        f32x4 acc[8];
        #pragma unroll
        for (int nt = 0; nt < 8; ++nt) {
            float4 bb = *(const float4*)(b1s + nt * 16 + quad * 4);
            acc[nt] = (f32x4){bb.x, bb.y, bb.z, bb.w};
        }
        #pragma unroll
        for (int ks = 0; ks < 8; ++ks) {
            bf16x8 bh = *(const bf16x8*)(hw + l15 * 264 + ks * 32 + quad * 8);
            #pragma unroll
            for (int nt = 0; nt < 8; ++nt) {
                bf16x8 aw = *(const bf16x8*)(W1s + ((ks * 8 + nt) * 64 + lane) * 8);
                acc[nt] = __builtin_amdgcn_mfma_f32_16x16x32_bf16(aw, bh, acc[nt], 0, 0, 0);
            }
        }

        if constexpr (TAIL) {
            // intra-wave WAR: hs reads complete before ew overwrite
            __asm__ __volatile__("s_waitcnt lgkmcnt(0)" ::: "memory");
            #pragma unroll
            for (int nt = 0; nt < 8; ++nt) {
                uint2 pv = {pack2(acc[nt][0], acc[nt][1]), pack2(acc[nt][2], acc[nt][3])};
                *(uint2*)(ew + l15 * 136 + nt * 16 + quad * 4) = pv;
            }

            // t = e @ M, SWAPPED (A=Mf frag, B=e frag) -> D=(e@M)^T:
            // lane holds t[row=wrow0+l15][cols nt*16+quad*4 .. +3]
            f32x4 tacc[2] = {{0.f,0.f,0.f,0.f},{0.f,0.f,0.f,0.f}};
            #pragma unroll
            for (int ks = 0; ks < 4; ++ks) {
                bf16x8 ae = *(const bf16x8*)(ew + l15 * 136 + ks * 32 + quad * 8);
                #pragma unroll
                for (int nt = 0; nt < 2; ++nt) {
                    bf16x8 bm = *(const bf16x8*)(Mfs + ((ks * 2 + nt) * 64 + lane) * 8);
                    tacc[nt] = __builtin_amdgcn_mfma_f32_16x16x32_bf16(bm, ae, tacc[nt], 0, 0, 0);
                }
            }
            #pragma unroll
            for (int nt = 0; nt < 2; ++nt) {
                uint2 pv = {pack2n(tacc[nt][0], tacc[nt][1]), pack2n(tacc[nt][2], tacc[nt][3])};
                *(uint2*)(tR + (size_t)(wrow0 + l15) * 32 + nt * 16 + quad * 4) = pv;
            }

            // per-b sums in registers (cols 2*lane, 2*lane+1); flush at b bounds
            #pragma unroll
            for (int r = 0; r < 16; ++r) {
                int b = (wrow0 + r) / NPB;
                if (b != bcur) {
                    bool interior = (bcur * NPB >= R0) && ((bcur + 1) * NPB <= R0 + 128);
                    float* dst = sumB + (size_t)bcur * 128 + 2 * lane;
                    if (interior) { dst[0] = s0; dst[1] = s1; }
                    else { atomicAdd(dst, s0); atomicAdd(dst + 1, s1); }
                    s0 = 0.f; s1 = 0.f; bcur = b;
                }
                unsigned v = *(const unsigned*)(ew + r * 136 + lane * 2);
                s0 += b2f((unsigned short)v);
                s1 += b2f((unsigned short)(v >> 16));
            }
            if (sub == 7) {
                bool interior = (bcur * NPB >= R0) && ((bcur + 1) * NPB <= R0 + 128);
                float* dst = sumB + (size_t)bcur * 128 + 2 * lane;
                if (interior) { dst[0] = s0; dst[1] = s1; }
                else { atomicAdd(dst, s0); atomicAdd(dst + 1, s1); }
            }
        } else {
            // root: direct row-major global store eR[row][n]
            #pragma unroll
            for (int nt = 0; nt < 8; ++nt) {
                uint2 pv = {pack2(acc[nt][0], acc[nt][1]), pack2(acc[nt][2], acc[nt][3])};
                *(uint2*)(eR + (size_t)(wrow0 + l15) * 128 + nt * 16 + quad * 4) = pv;
            }
        }
        __asm__ __volatile__("" ::: "memory");   // keep iteration LDS order
    }
}

__global__ __launch_bounds__(512, 2) void k_mlpE(
    const float* __restrict__ state,
    const unsigned short* __restrict__ W0b_h, const float* __restrict__ b0_h,
    const unsigned short* __restrict__ W1f_h, const float* __restrict__ b1_h,
    const unsigned short* __restrict__ Mf_h, unsigned short* __restrict__ tR_h,
    float* __restrict__ shB,
    const unsigned short* __restrict__ W0b_o, const float* __restrict__ b0_o,
    const unsigned short* __restrict__ W1f_o, const float* __restrict__ b1_o,
    const unsigned short* __restrict__ Mf_o, unsigned short* __restrict__ tR_o,
    float* __restrict__ soB,
    const unsigned short* __restrict__ W0b_r, const float* __restrict__ b0_r,
    const unsigned short* __restrict__ W1f_r, const float* __restrict__ b1_r,
    unsigned short* __restrict__ eR)
{
    __shared__ __align__(16) char smem[SM_SZ];
    int bid = blockIdx.x;
    if (bid < 160)
        mlp_blockE<20, 0, 6, 7, true>(bid * 1024, state, W0b_h, b0_h, W1f_h, b1_h,
                                      Mf_h, tR_h, shB, nullptr, smem);
    else if (bid < 240)
        mlp_blockE<10, 20, 6, 7, true>((bid - 160) * 1024, state, W0b_o, b0_o, W1f_o, b1_o,
                                       Mf_o, tR_o, soB, nullptr, smem);
    else
        mlp_blockE<1, 0, 0, 6, false>((bid - 240) * 1024, state, W0b_r, b0_r, W1f_r, b1_r,
                                      nullptr, nullptr, nullptr, eR, smem);
}

// ---------------------------------------------------------------------------
// k_tail: FUSED u2 + sM + v, 16 b's per block, 512 blocks (2 blocks/CU,
// two independent barrier groups per CU). M=16 fills the MFMA exactly;
// N-tiles strided across the 4 waves.
// LDS 33KB: Ub[16][400] (V1b aliases) | Vb[16][104] | chL/coL | Hb | V2b
// ---------------------------------------------------------------------------
__global__ __launch_bounds__(256, 2) void k_tail(
    const unsigned short* __restrict__ eR,
    const float* __restrict__ shB, const float* __restrict__ soB,
    const unsigned short* __restrict__ tR_h, const unsigned short* __restrict__ tR_o,
    const unsigned short* __restrict__ Wcatf, const float* __restrict__ bcat,
    const unsigned short* __restrict__ Wc2f, const float* __restrict__ bc2,
    const unsigned short* __restrict__ vW0f, const float* __restrict__ vb0,
    const unsigned short* __restrict__ vW1f, const float* __restrict__ vb1,
    const float* __restrict__ vW2, const float* __restrict__ vb2,
    float* __restrict__ out)
{
    __shared__ __align__(16) char sm[33024];
    unsigned short* Ub  = (unsigned short*)(sm);          // [16][400]
    unsigned short* V1b = (unsigned short*)(sm);          // alias  [16][264]
    unsigned short* Vb  = (unsigned short*)(sm + 12800);  // [16][104]
    float* chL          = (float*)(sm + 16128);           // [16][32]
    float* coL          = (float*)(sm + 18176);           // [16][32]
    unsigned short* Hb  = (unsigned short*)(sm + 20224);  // [16][136]
    float* V2b          = (float*)(sm + 24576);           // [16][132]

    const int t = threadIdx.x, lane = t & 63, w = t >> 6;
    const int l15 = lane & 15, quad = lane >> 4;
    const int b0 = blockIdx.x * 16;
    const int rowb = quad * 4;

    // ---- phase 1: stage U = [er | sh | so] ----
    {
        int b = t >> 4, q = t & 15;
        ((uint4*)(Ub + b * 400))[q] = ((const uint4*)(eR + (size_t)(b0 + b) * 128))[q];
    }
    for (int idx = t; idx < 4096; idx += 256) {
        int b = idx >> 8, kk = idx & 255;
        float v = (kk < 128) ? shB[(size_t)(b0 + b) * 128 + kk]
                             : soB[(size_t)(b0 + b) * 128 + kk - 128];
        Ub[b * 400 + 128 + kk] = f2b(v);
    }
    __syncthreads();

    // ---- phase 2: U-MFMA (unswapped, verified): xr / ch / co ----
    for (int nt = w; nt < 6; nt += 4) {
        float bias = bcat[nt * 16 + l15];
        f32x4 acc = {bias, bias, bias, bias};
        #pragma unroll
        for (int ks = 0; ks < 12; ++ks) {
            bf16x8 a = *(const bf16x8*)(Ub + l15 * 400 + ks * 32 + quad * 8);
            bf16x8 bw = *(const bf16x8*)(Wcatf + ((ks * 6 + nt) * 64 + lane) * 8);
            acc = __builtin_amdgcn_mfma_f32_16x16x32_bf16(a, bw, acc, 0, 0, 0);
        }
        int n = nt * 16 + l15;
        #pragma unroll
        for (int reg = 0; reg < 4; ++reg) {
            float v = acc[reg];
            int b = rowb + reg;
            if (n < 32)      Vb[b * 104 + n] = f2b(fmaxf(v, 0.f));
            else if (n < 64) chL[b * 32 + (n - 32)] = v;
            else             coL[b * 32 + (n - 64)] = v;
        }
    }
    __syncthreads();

    // ---- phase 3: t-scan (row-major tR, coalesced) -> s2h, s2o ----
    for (int idx = t; idx < 512; idx += 256) {
        int b = idx >> 5, m = idx & 31;
        float ch = chL[b * 32 + m];
        const unsigned short* p = tR_h + (size_t)(b0 + b) * 20 * 32 + m;
        float s = 0.f;
        #pragma unroll
        for (int n = 0; n < 20; ++n) s += fmaxf(ch + b2f(p[n * 32]), 0.f);
        Vb[b * 104 + 32 + m] = f2b(s);
        float co = coL[b * 32 + m];
        const unsigned short* p2 = tR_o + (size_t)(b0 + b) * 10 * 32 + m;
        float s2 = 0.f;
        #pragma unroll
        for (int n = 0; n < 10; ++n) s2 += fmaxf(co + b2f(p2[n * 32]), 0.f);
        Vb[b * 104 + 64 + m] = f2b(s2);
    }
    __syncthreads();

    // ---- phase 4: c2 (N=128, 2 nt per wave) ----
    {
        f32x4 acc[2];
        #pragma unroll
        for (int q = 0; q < 2; ++q) {
            int nt = w + q * 4;
            float bias = bc2[nt * 16 + l15];
            acc[q] = (f32x4){bias, bias, bias, bias};
        }
        #pragma unroll
        for (int ks = 0; ks < 3; ++ks) {
            bf16x8 a = *(const bf16x8*)(Vb + l15 * 104 + ks * 32 + quad * 8);
            #pragma unroll
            for (int q = 0; q < 2; ++q) {
                int nt = w + q * 4;
                bf16x8 bw = *(const bf16x8*)(Wc2f + ((ks * 8 + nt) * 64 + lane) * 8);
                acc[q] = __builtin_amdgcn_mfma_f32_16x16x32_bf16(a, bw, acc[q], 0, 0, 0);
            }
        }
        #pragma unroll
        for (int q = 0; q < 2; ++q) {
            int nt = w + q * 4;
            #pragma unroll
            for (int reg = 0; reg < 4; ++reg)
                Hb[(rowb + reg) * 136 + nt * 16 + l15] = f2b(fmaxf(acc[q][reg], 0.f));
        }
    }
    __syncthreads();

    // ---- phase 5: v1 (N=256, 4 nt per wave; V1b aliases dead Ub) ----
    {
        f32x4 acc[4];
        #pragma unroll
        for (int q = 0; q < 4; ++q) {
            int nt = w + q * 4;
            float bias = vb0[nt * 16 + l15];
            acc[q] = (f32x4){bias, bias, bias, bias};
        }
        #pragma unroll
        for (int ks = 0; ks < 4; ++ks) {
            bf16x8 a = *(const bf16x8*)(Hb + l15 * 136 + ks * 32 + quad * 8);
            #pragma unroll
            for (int q = 0; q < 4; ++q) {
                int nt = w + q * 4;
                bf16x8 bw = *(const bf16x8*)(vW0f + ((ks * 16 + nt) * 64 + lane) * 8);
                acc[q] = __builtin_amdgcn_mfma_f32_16x16x32_bf16(a, bw, acc[q], 0, 0, 0);
            }
        }
        __syncthreads();   // Ub reads (phase-2 done long ago) -> safe; order vs writes
        #pragma unroll
        for (int q = 0; q < 4; ++q) {
            int nt = w + q * 4;
            #pragma unroll
            for (int reg = 0; reg < 4; ++reg)
                V1b[(rowb + reg) * 264 + nt * 16 + l15] = f2b(fmaxf(acc[q][reg], 0.f));
        }
    }
    __syncthreads();

    // ---- phase 6: v2 (N=128, 2 nt per wave) ----
    {
        f32x4 acc[2];
        #pragma unroll
        for (int q = 0; q < 2; ++q) {
            int nt = w + q * 4;
            float bias = vb1[nt * 16 + l15];
            acc[q] = (f32x4){bias, bias, bias, bias};
        }
        #pragma unroll
        for (int ks = 0; ks < 8; ++ks) {
            bf16x8 a = *(const bf16x8*)(V1b + l15 * 264 + ks * 32 + quad * 8);
            #pragma unroll
            for (int q = 0; q < 2; ++q) {
                int nt = w + q * 4;
                bf16x8 bw = *(const bf16x8*)(vW1f + ((ks * 8 + nt) * 64 + lane) * 8);
                acc[q] = __builtin_amdgcn_mfma_f32_16x16x32_bf16(a, bw, acc[q], 0, 0, 0);
            }
        }
        #pragma unroll
        for (int q = 0; q < 2; ++q) {
            int nt = w + q * 4;
            #pragma unroll
            for (int reg = 0; reg < 4; ++reg)
                V2b[(rowb + reg) * 132 + nt * 16 + l15] = fmaxf(acc[q][reg], 0.f);
        }
    }
    __syncthreads();

    // ---- phase 7: v3, 8 threads per b + shuffle reduce ----
    if (t < 128) {
        int b = t >> 3, j = t & 7;
        float v = 0.f;
        #pragma unroll
        for (int k = 0; k < 16; ++k)
            v = fmaf(V2b[b * 132 + j * 16 + k], vW2[j * 16 + k], v);
        v += __shfl_down(v, 4, 8);
        v += __shfl_down(v, 2, 8);
        v += __shfl_down(v, 1, 8);
        if (j == 0) out[b0 + b] = v + vb2[0];
    }
}

// ---------------------------------------------------------------------------
extern "C" void kernel_launch(void* const* d_in, const int* in_sizes, int n_in,
                              void* d_out, int out_size, void* d_ws, size_t ws_size,
                              hipStream_t stream)
{
    const float* state   = (const float*)d_in[0];
    const float* wr_W0   = (const float*)d_in[2];
    const float* wr_b0   = (const float*)d_in[3];
    const float* wr_W1   = (const float*)d_in[4];
    const float* wr_b1   = (const float*)d_in[5];
    const float* wh_W0   = (const float*)d_in[6];
    const float* wh_b0   = (const float*)d_in[7];
    const float* wh_W1   = (const float*)d_in[8];
    const float* wh_b1   = (const float*)d_in[9];
    const float* wo_W0   = (const float*)d_in[10];
    const float* wo_b0   = (const float*)d_in[11];
    const float* wo_W1   = (const float*)d_in[12];
    const float* wo_b1   = (const float*)d_in[13];
    const float* c1_relW = (const float*)d_in[14];
    const float* c1_relb = (const float*)d_in[15];
    const float* c1_rootW= (const float*)d_in[16];
    const float* c2_relW = (const float*)d_in[17];
    const float* c2_relb = (const float*)d_in[18];
    const float* c2_rootW= (const float*)d_in[19];
    const float* v_W0    = (const float*)d_in[20];
    const float* v_b0    = (const float*)d_in[21];
    const float* v_W1    = (const float*)d_in[22];
    const float* v_b1    = (const float*)d_in[23];
    const float* v_W2    = (const float*)d_in[24];
    const float* v_b2    = (const float*)d_in[25];

    char* ws = (char*)d_ws;
    size_t off = 0;
    auto alloc = [&](size_t bytes) -> char* {
        char* p = ws + off;
        off = (off + bytes + 255) & ~(size_t)255;
        return p;
    };
    float* shB  = (float*)alloc((size_t)BATCH * 128 * 4);          // b-major sums
    float* soB  = (float*)alloc((size_t)BATCH * 128 * 4);          // contiguous with shB
    unsigned short* tR_h = (unsigned short*)alloc((size_t)163840 * 32 * 2);  // row-major
    unsigned short* tR_o = (unsigned short*)alloc((size_t)81920 * 32 * 2);   // row-major
    unsigned short* eR   = (unsigned short*)alloc((size_t)BATCH * 128 * 2);
    float* bcat = (float*)alloc(96 * 4);
    float* bc2  = (float*)alloc(128 * 4);
    unsigned short* W0b_h = (unsigned short*)alloc(2048 * 2);
    unsigned short* W0b_o = (unsigned short*)alloc(2048 * 2);
    unsigned short* W0b_r = (unsigned short*)alloc(2048 * 2);
    unsigned short* W1f_h = (unsigned short*)alloc(32768 * 2);
    unsigned short* W1f_o = (unsigned short*)alloc(32768 * 2);
    unsigned short* W1f_r = (unsigned short*)alloc(32768 * 2);
    unsigned short* Mf_h  = (unsigned short*)alloc(4096 * 2);
    unsigned short* Mf_o  = (unsigned short*)alloc(4096 * 2);
    unsigned short* Wcatf = (unsigned short*)alloc(36864 * 2);
    unsigned short* Wc2f  = (unsigned short*)alloc(12288 * 2);
    unsigned short* vW0f  = (unsigned short*)alloc(32768 * 2);
    unsigned short* vW1f  = (unsigned short*)alloc(32768 * 2);
    (void)ws_size; (void)in_sizes; (void)n_in; (void)out_size;

    hipMemsetAsync(shB, 0, (size_t)2 * BATCH * 128 * 4, stream);

    k_prep<<<256, 256, 0, stream>>>(c1_relW, c1_relb, c1_rootW, c2_relW, c2_relb, c2_rootW,
                                    wh_W0, wh_W1, wo_W0, wo_W1, wr_W0, wr_W1, v_W0, v_W1,
                                    bcat, bc2, W0b_h, W0b_o, W0b_r, W1f_h, W1f_o, W1f_r,
                                    Mf_h, Mf_o, Wcatf, Wc2f, vW0f, vW1f);

    k_mlpE<<<248, 512, 0, stream>>>(state,
                                    W0b_h, wh_b0, W1f_h, wh_b1, Mf_h, tR_h, shB,
                                    W0b_o, wo_b0, W1f_o, wo_b1, Mf_o, tR_o, soB,
                                    W0b_r, wr_b0, W1f_r, wr_b1, eR);

    k_tail<<<512, 256, 0, stream>>>(eR, shB, soB, tR_h, tR_o,
                                    Wcatf, bcat, Wc2f, bc2, vW0f, v_b0, vW1f, v_b1,
                                    v_W2, v_b2, (float*)d_out);
}